// Round 1
// baseline (2725.501 us; speedup 1.0000x reference)
//
#include <hip/hip_runtime.h>
#include <math.h>

#define BB   16
#define CC   512
#define HWW  576
#define NN   9216            // B*HW
#define CHW  (CC*HWW)        // 294912
#define TOT  (BB*CHW)        // 4718592

// ---------------------------------------------------------------------------
// K1/K2/K3: 1x1 conv as GEMM.  Y[b,o,m] = sum_c W[o,c]*X[b,c,m] + bias[o]
// (+ X[b,o,m] when RES).  64x64 output tile, K-chunk 32, 4x4 microtile.
// n-tiles (64 pixels) never cross a batch boundary since 576 % 64 == 0.
// ---------------------------------------------------------------------------
template<int RES>
__global__ __launch_bounds__(256)
void conv1x1_kernel(const float* __restrict__ X, const float* __restrict__ W,
                    const float* __restrict__ bias, float* __restrict__ Y)
{
    __shared__ float Ws[32][65];
    __shared__ float Xs[32][65];
    int tid = threadIdx.x;
    int tx = tid & 15, ty = tid >> 4;
    int n0 = blockIdx.x * 64;
    int o0 = blockIdx.y * 64;
    int b  = n0 / HWW;
    int m0 = n0 % HWW;

    float acc[4][4];
#pragma unroll
    for (int i = 0; i < 4; i++)
#pragma unroll
        for (int j = 0; j < 4; j++) acc[i][j] = 0.f;

    for (int c0 = 0; c0 < CC; c0 += 32) {
#pragma unroll
        for (int e = tid; e < 64 * 32; e += 256) {
            int kk = e & 31, oi = e >> 5;
            Ws[kk][oi] = W[(o0 + oi) * CC + c0 + kk];
        }
#pragma unroll
        for (int e = tid; e < 32 * 64; e += 256) {
            int mi = e & 63, kk = e >> 6;
            Xs[kk][mi] = X[b * CHW + (c0 + kk) * HWW + m0 + mi];
        }
        __syncthreads();
#pragma unroll
        for (int kk = 0; kk < 32; kk++) {
            float a[4], bv[4];
#pragma unroll
            for (int i = 0; i < 4; i++) a[i] = Ws[kk][ty * 4 + i];
#pragma unroll
            for (int j = 0; j < 4; j++) bv[j] = Xs[kk][tx * 4 + j];
#pragma unroll
            for (int i = 0; i < 4; i++)
#pragma unroll
                for (int j = 0; j < 4; j++)
                    acc[i][j] = fmaf(a[i], bv[j], acc[i][j]);
        }
        __syncthreads();
    }

#pragma unroll
    for (int i = 0; i < 4; i++) {
        int o = o0 + ty * 4 + i;
        float bo = bias[o];
#pragma unroll
        for (int j = 0; j < 4; j++) {
            int m = m0 + tx * 4 + j;
            int idx = b * CHW + o * HWW + m;
            float v = acc[i][j] + bo;
            if (RES) v += X[idx];
            Y[idx] = v;
        }
    }
}

// ---------------------------------------------------------------------------
// K4: fused scores GEMM + max over key locations.
// maxv[n][b] = scale * max_m sum_c Q[bq,c,mq] * K[b,c,m]
// Block = (64-query tile, one key image).  Never materializes scores.
// ---------------------------------------------------------------------------
__global__ __launch_bounds__(256)
void scores_max_kernel(const float* __restrict__ Q, const float* __restrict__ Km,
                       float* __restrict__ maxv)
{
    __shared__ float qs[32][65];
    __shared__ float ks[32][65];
    __shared__ float red[64][16];
    int tid = threadIdx.x;
    int tx = tid & 15, ty = tid >> 4;
    int n0 = blockIdx.x * 64;
    int b  = blockIdx.y;
    int bq = n0 / HWW, mq0 = n0 % HWW;

    float runmax[4];
#pragma unroll
    for (int i = 0; i < 4; i++) runmax[i] = -3.4e38f;

    for (int mt = 0; mt < 9; mt++) {
        int m0 = mt * 64;
        float acc[4][4];
#pragma unroll
        for (int i = 0; i < 4; i++)
#pragma unroll
            for (int j = 0; j < 4; j++) acc[i][j] = 0.f;

        for (int c0 = 0; c0 < CC; c0 += 32) {
#pragma unroll
            for (int e = tid; e < 2048; e += 256) {
                int ni = e & 63, kk = e >> 6;
                qs[kk][ni] = Q[bq * CHW + (c0 + kk) * HWW + mq0 + ni];
                ks[kk][ni] = Km[b * CHW + (c0 + kk) * HWW + m0 + ni];
            }
            __syncthreads();
#pragma unroll
            for (int kk = 0; kk < 32; kk++) {
                float a[4], bv[4];
#pragma unroll
                for (int i = 0; i < 4; i++) a[i] = qs[kk][ty * 4 + i];
#pragma unroll
                for (int j = 0; j < 4; j++) bv[j] = ks[kk][tx * 4 + j];
#pragma unroll
                for (int i = 0; i < 4; i++)
#pragma unroll
                    for (int j = 0; j < 4; j++)
                        acc[i][j] = fmaf(a[i], bv[j], acc[i][j]);
            }
            __syncthreads();
        }
#pragma unroll
        for (int i = 0; i < 4; i++)
#pragma unroll
            for (int j = 0; j < 4; j++)
                runmax[i] = fmaxf(runmax[i], acc[i][j]);
    }

#pragma unroll
    for (int i = 0; i < 4; i++) red[ty * 4 + i][tx] = runmax[i];
    __syncthreads();
    if (tid < 64) {
        float mx = red[tid][0];
        for (int t = 1; t < 16; t++) mx = fmaxf(mx, red[tid][t]);
        maxv[(n0 + tid) * BB + b] = mx * 0.044194173824159216f; // 1/sqrt(512)
    }
}

// ---------------------------------------------------------------------------
// K5: v[n] = mean_b maxv[n][b]; per-image softmax over 576; equality-based
// top-1 mask (replicates reference fp32 semantics exactly).
// ---------------------------------------------------------------------------
__global__ __launch_bounds__(576)
void softmax_mask_kernel(const float* __restrict__ maxv, float* __restrict__ maskout)
{
    __shared__ float sv[576];
    __shared__ float sred[64];
    __shared__ float s_vmax, s_sum, s_wmax;
    int b = blockIdx.x;
    int m = threadIdx.x;

    float v = 0.f;
#pragma unroll
    for (int t = 0; t < BB; t++) v += maxv[(b * HWW + m) * BB + t];
    v *= (1.0f / 16.0f);
    sv[m] = v;
    __syncthreads();
    if (m < 64) {
        float x = sv[m];
        for (int j = m + 64; j < 576; j += 64) x = fmaxf(x, sv[j]);
        sred[m] = x;
    }
    __syncthreads();
    if (m == 0) { float x = sred[0]; for (int j = 1; j < 64; j++) x = fmaxf(x, sred[j]); s_vmax = x; }
    __syncthreads();
    float e = expf(v - s_vmax);
    sv[m] = e;
    __syncthreads();
    if (m < 64) { float x = 0.f; for (int j = m; j < 576; j += 64) x += sv[j]; sred[m] = x; }
    __syncthreads();
    if (m == 0) { float x = 0.f; for (int j = 0; j < 64; j++) x += sred[j]; s_sum = x; }
    __syncthreads();
    float xw = e / s_sum;
    sv[m] = xw;
    __syncthreads();
    if (m < 64) { float x = sv[m]; for (int j = m + 64; j < 576; j += 64) x = fmaxf(x, sv[j]); sred[m] = x; }
    __syncthreads();
    if (m == 0) { float x = sred[0]; for (int j = 1; j < 64; j++) x = fmaxf(x, sred[j]); s_wmax = x; }
    __syncthreads();
    maskout[b * HWW + m] = (xw == s_wmax) ? 1.0f : 0.0f;
}

// ---------------------------------------------------------------------------
// K6: inv[b,m] = 1/max(sqrt(sum_c x5^2), 1e-12)
// ---------------------------------------------------------------------------
__global__ __launch_bounds__(256)
void norm_kernel(const float* __restrict__ X5, float* __restrict__ invb)
{
    int b = blockIdx.y;
    int m0 = blockIdx.x * 64;
    int mi = threadIdx.x & 63, cs = threadIdx.x >> 6;
    float s = 0.f;
    for (int c = cs; c < CC; c += 4) {
        float x = X5[b * CHW + c * HWW + m0 + mi];
        s = fmaf(x, x, s);
    }
    __shared__ float red[4][64];
    red[cs][mi] = s;
    __syncthreads();
    if (cs == 0) {
        float t = red[0][mi] + red[1][mi] + red[2][mi] + red[3][mi];
        invb[b * HWW + m0 + mi] = 1.0f / fmaxf(sqrtf(t), 1e-12f);
    }
}

// ---------------------------------------------------------------------------
// K7: seeds[s,c] = sum_m x5[s,c,m] * inv[s,m] * mask[s,m]
// ---------------------------------------------------------------------------
__global__ __launch_bounds__(256)
void seeds_kernel(const float* __restrict__ X5, const float* __restrict__ invb,
                  const float* __restrict__ maskf, float* __restrict__ seeds)
{
    int s = blockIdx.y;
    int c = blockIdx.x * 4 + (threadIdx.x >> 6);
    int mi = threadIdx.x & 63;
    float acc = 0.f;
    for (int mt = 0; mt < 9; mt++) {
        int m = mt * 64 + mi;
        float w = invb[s * HWW + m] * maskf[s * HWW + m];
        acc = fmaf(X5[s * CHW + c * HWW + m], w, acc);
    }
    for (int off = 32; off > 0; off >>= 1) acc += __shfl_down(acc, off, 64);
    if (mi == 0) seeds[s * CC + c] = acc;
}

// ---------------------------------------------------------------------------
// K8: corr[b,m] = inv[b,m]/16 * sum_s relu( sum_c x5[b,c,m]*seeds[s,c] )
// (inv > 0 so relu commutes with the scale)
// ---------------------------------------------------------------------------
__global__ __launch_bounds__(256)
void corr_kernel(const float* __restrict__ X5, const float* __restrict__ invb,
                 const float* __restrict__ seeds, float* __restrict__ corr)
{
    __shared__ float sd[16 * 512];   // all seeds: 32 KB
    __shared__ float xs[64][65];
    __shared__ float red[4][64];
    int b = blockIdx.y;
    int m0 = blockIdx.x * 64;
    int tid = threadIdx.x;
    int mi = tid & 63, sg = tid >> 6;

    for (int e = tid; e < 16 * 512; e += 256) sd[e] = seeds[e];

    float acc[4] = {0.f, 0.f, 0.f, 0.f};
    for (int c0 = 0; c0 < CC; c0 += 64) {
        __syncthreads();
        for (int e = tid; e < 4096; e += 256) {
            int mm = e & 63, kk = e >> 6;
            xs[kk][mm] = X5[b * CHW + (c0 + kk) * HWW + m0 + mm];
        }
        __syncthreads();
#pragma unroll
        for (int kk = 0; kk < 64; kk++) {
            float xv = xs[kk][mi];
#pragma unroll
            for (int t = 0; t < 4; t++)
                acc[t] = fmaf(xv, sd[(sg * 4 + t) * CC + c0 + kk], acc[t]);
        }
    }
    float r = 0.f;
#pragma unroll
    for (int t = 0; t < 4; t++) r += fmaxf(acc[t], 0.f);
    red[sg][mi] = r;
    __syncthreads();
    if (sg == 0) {
        float tot = red[0][mi] + red[1][mi] + red[2][mi] + red[3][mi];
        corr[b * HWW + m0 + mi] = invb[b * HWW + m0 + mi] * tot * (1.0f / 16.0f);
    }
}

// ---------------------------------------------------------------------------
// K9: per-image min/max normalize of corr -> cormap
// ---------------------------------------------------------------------------
__global__ __launch_bounds__(576)
void cormap_kernel(const float* __restrict__ corr, float* __restrict__ cormap)
{
    __shared__ float sv[576];
    __shared__ float smn[64], smx[64];
    __shared__ float s_mn, s_mx;
    int b = blockIdx.x;
    int m = threadIdx.x;
    float v = corr[b * HWW + m];
    sv[m] = v;
    __syncthreads();
    if (m < 64) {
        float mn = sv[m], mx = sv[m];
        for (int j = m + 64; j < 576; j += 64) { mn = fminf(mn, sv[j]); mx = fmaxf(mx, sv[j]); }
        smn[m] = mn; smx[m] = mx;
    }
    __syncthreads();
    if (m == 0) {
        float mn = smn[0], mx = smx[0];
        for (int j = 1; j < 64; j++) { mn = fminf(mn, smn[j]); mx = fmaxf(mx, smx[j]); }
        s_mn = mn; s_mx = mx;
    }
    __syncthreads();
    cormap[b * HWW + m] = (v - s_mn) / (s_mx - s_mn + 1e-12f);
}

// ---------------------------------------------------------------------------
// K10: proto1[c] = mean_{b,m} x5[b,c,m]*cormap[b,m]
// ---------------------------------------------------------------------------
__global__ __launch_bounds__(256)
void proto_kernel(const float* __restrict__ X5, const float* __restrict__ cormap,
                  float* __restrict__ proto1)
{
    int c = blockIdx.x;
    int tid = threadIdx.x;
    float acc = 0.f;
    for (int p = tid; p < NN; p += 256) {
        int b = p / HWW, m = p % HWW;
        acc = fmaf(X5[b * CHW + c * HWW + m], cormap[p], acc);
    }
    for (int off = 32; off > 0; off >>= 1) acc += __shfl_down(acc, off, 64);
    __shared__ float red[4];
    if ((tid & 63) == 0) red[tid >> 6] = acc;
    __syncthreads();
    if (tid == 0) proto1[c] = (red[0] + red[1] + red[2] + red[3]) * (1.0f / (float)NN);
}

// ---------------------------------------------------------------------------
// K11: out3 = x5*proto1 + x5*cormap = x5*(proto1[c] + cormap[b,m])
// ---------------------------------------------------------------------------
__global__ __launch_bounds__(256)
void final_kernel(const float* __restrict__ X5, const float* __restrict__ proto1,
                  const float* __restrict__ cormap, float* __restrict__ out3)
{
    int idx = blockIdx.x * 256 + threadIdx.x;
    if (idx >= TOT) return;
    int b = idx / CHW;
    int r = idx % CHW;
    int c = r / HWW;
    int m = r % HWW;
    float x = X5[idx];
    out3[idx] = x * (proto1[c] + cormap[b * HWW + m]);
}

// ---------------------------------------------------------------------------
extern "C" void kernel_launch(void* const* d_in, const int* in_sizes, int n_in,
                              void* d_out, int out_size, void* d_ws, size_t ws_size,
                              hipStream_t stream)
{
    const float* x  = (const float*)d_in[0];
    const float* cw = (const float*)d_in[1];
    const float* cb = (const float*)d_in[2];
    const float* qw = (const float*)d_in[3];
    const float* qb = (const float*)d_in[4];
    const float* kw = (const float*)d_in[5];
    const float* kb = (const float*)d_in[6];

    float* out     = (float*)d_out;
    float* x5o     = out;                        // output 0 (B,C,H,W)
    float* proto1  = out + TOT;                  // output 1 (512)
    float* out3    = out + TOT + 512;            // output 2 (B,C,H,W)
    float* maskout = out + TOT + 512 + TOT;      // output 3 (B,1,H,W)

    float* ws    = (float*)d_ws;
    float* kbuf  = ws;                 // TOT floats
    float* maxv  = ws + TOT;           // NN*BB
    float* invb  = maxv + NN * BB;     // NN
    float* corr  = invb + NN;          // NN
    float* cmap  = corr + NN;          // NN
    float* seeds = cmap + NN;          // BB*CC
    float* qbuf  = out3;               // stage q in out3 region (overwritten last)

    dim3 gg(NN / 64, CC / 64);
    conv1x1_kernel<1><<<gg, 256, 0, stream>>>(x, cw, cb, x5o);
    conv1x1_kernel<0><<<gg, 256, 0, stream>>>(x5o, qw, qb, qbuf);
    conv1x1_kernel<0><<<gg, 256, 0, stream>>>(x5o, kw, kb, kbuf);
    scores_max_kernel<<<dim3(NN / 64, BB), 256, 0, stream>>>(qbuf, kbuf, maxv);
    softmax_mask_kernel<<<BB, HWW, 0, stream>>>(maxv, maskout);
    norm_kernel<<<dim3(9, BB), 256, 0, stream>>>(x5o, invb);
    seeds_kernel<<<dim3(CC / 4, BB), 256, 0, stream>>>(x5o, invb, maskout, seeds);
    corr_kernel<<<dim3(9, BB), 256, 0, stream>>>(x5o, invb, seeds, corr);
    cormap_kernel<<<BB, HWW, 0, stream>>>(corr, cmap);
    proto_kernel<<<CC, 256, 0, stream>>>(x5o, cmap, proto1);
    final_kernel<<<(TOT + 255) / 256, 256, 0, stream>>>(x5o, proto1, cmap, out3);
}

// Round 2
// 816.285 us; speedup vs baseline: 3.3389x; 3.3389x over previous
//
#include <hip/hip_runtime.h>
#include <math.h>

#define BB   16
#define CC   512
#define HWW  576
#define NN   9216            // B*HW
#define CHW  (CC*HWW)        // 294912
#define TOT  (BB*CHW)        // 4718592
#define SCALE 0.044194173824159216f  // 1/sqrt(512)

typedef __attribute__((ext_vector_type(8))) __bf16 bf16x8;
typedef __attribute__((ext_vector_type(4))) float f32x4;

// ---------------------------------------------------------------------------
// Fragment-linear bf16 layout for MFMA operands.
// 64-pixel x 64-channel block -> 4096 bf16, blocks indexed [C=c>>6][T=n>>6]
// (C-major, T stride 4096). Within a block, slot(s,g4,L,j):
//   elem offset = (s*4+g4)*512 + L*8 + j
//   m64 = g4*16 + (L&15),  c64 = s*32 + ((L>>4)&3)*8 + j
// A-frag/B-frag read for mfma_16x16x32: contiguous 16B at lane*16. 
// ---------------------------------------------------------------------------

// K1: x5 conv (fp32, residual) — unchanged from round 1.
__global__ __launch_bounds__(256)
void conv1x1_res_kernel(const float* __restrict__ X, const float* __restrict__ W,
                        const float* __restrict__ bias, float* __restrict__ Y)
{
    __shared__ float Ws[32][65];
    __shared__ float Xs[32][65];
    int tid = threadIdx.x;
    int tx = tid & 15, ty = tid >> 4;
    int n0 = blockIdx.x * 64;
    int o0 = blockIdx.y * 64;
    int b  = n0 / HWW;
    int m0 = n0 % HWW;

    float acc[4][4];
#pragma unroll
    for (int i = 0; i < 4; i++)
#pragma unroll
        for (int j = 0; j < 4; j++) acc[i][j] = 0.f;

    for (int c0 = 0; c0 < CC; c0 += 32) {
#pragma unroll
        for (int e = tid; e < 64 * 32; e += 256) {
            int kk = e & 31, oi = e >> 5;
            Ws[kk][oi] = W[(o0 + oi) * CC + c0 + kk];
        }
#pragma unroll
        for (int e = tid; e < 32 * 64; e += 256) {
            int mi = e & 63, kk = e >> 6;
            Xs[kk][mi] = X[b * CHW + (c0 + kk) * HWW + m0 + mi];
        }
        __syncthreads();
#pragma unroll
        for (int kk = 0; kk < 32; kk++) {
            float a[4], bv[4];
#pragma unroll
            for (int i = 0; i < 4; i++) a[i] = Ws[kk][ty * 4 + i];
#pragma unroll
            for (int j = 0; j < 4; j++) bv[j] = Xs[kk][tx * 4 + j];
#pragma unroll
            for (int i = 0; i < 4; i++)
#pragma unroll
                for (int j = 0; j < 4; j++)
                    acc[i][j] = fmaf(a[i], bv[j], acc[i][j]);
        }
        __syncthreads();
    }

#pragma unroll
    for (int i = 0; i < 4; i++) {
        int o = o0 + ty * 4 + i;
        float bo = bias[o];
#pragma unroll
        for (int j = 0; j < 4; j++) {
            int m = m0 + tx * 4 + j;
            int idx = b * CHW + o * HWW + m;
            Y[idx] = acc[i][j] + bo + X[idx];
        }
    }
}

// K2/K3: q/k conv — fp32 GEMM, epilogue writes bf16 fragment-linear layout.
__global__ __launch_bounds__(256)
void convqk_frag_kernel(const float* __restrict__ X, const float* __restrict__ W,
                        const float* __restrict__ bias, __bf16* __restrict__ Of)
{
    __shared__ float Ws[32][65];
    __shared__ float Xs[32][65];
    int tid = threadIdx.x;
    int tx = tid & 15, ty = tid >> 4;
    int n0 = blockIdx.x * 64;
    int o0 = blockIdx.y * 64;
    int b  = n0 / HWW;
    int m0 = n0 % HWW;

    float acc[4][4];
#pragma unroll
    for (int i = 0; i < 4; i++)
#pragma unroll
        for (int j = 0; j < 4; j++) acc[i][j] = 0.f;

    for (int c0 = 0; c0 < CC; c0 += 32) {
#pragma unroll
        for (int e = tid; e < 64 * 32; e += 256) {
            int kk = e & 31, oi = e >> 5;
            Ws[kk][oi] = W[(o0 + oi) * CC + c0 + kk];
        }
#pragma unroll
        for (int e = tid; e < 32 * 64; e += 256) {
            int mi = e & 63, kk = e >> 6;
            Xs[kk][mi] = X[b * CHW + (c0 + kk) * HWW + m0 + mi];
        }
        __syncthreads();
#pragma unroll
        for (int kk = 0; kk < 32; kk++) {
            float a[4], bv[4];
#pragma unroll
            for (int i = 0; i < 4; i++) a[i] = Ws[kk][ty * 4 + i];
#pragma unroll
            for (int j = 0; j < 4; j++) bv[j] = Xs[kk][tx * 4 + j];
#pragma unroll
            for (int i = 0; i < 4; i++)
#pragma unroll
                for (int j = 0; j < 4; j++)
                    acc[i][j] = fmaf(a[i], bv[j], acc[i][j]);
        }
        __syncthreads();
    }

    int obase = o0 + ty * 4;
    int Cb = obase >> 6, s = (obase >> 5) & 1, cc3 = (obase >> 3) & 3, j0 = obase & 7;
    float bo[4];
#pragma unroll
    for (int i = 0; i < 4; i++) bo[i] = bias[obase + i];
#pragma unroll
    for (int j = 0; j < 4; j++) {
        int n = n0 + tx * 4 + j;                       // global pixel
        int T = n >> 6, g4 = (n >> 4) & 3, L = (n & 15) | (cc3 << 4);
        union { __bf16 h[4]; float2 f2; } u;
#pragma unroll
        for (int i = 0; i < 4; i++) u.h[i] = (__bf16)(acc[i][j] + bo[i]);
        *(float2*)&Of[(size_t)(Cb * 144 + T) * 4096 + ((s * 4 + g4) * 64 + L) * 8 + j0] = u.f2;
    }
}

// ---------------------------------------------------------------------------
// K4: scores GEMM on MFMA (bf16) + max over key locations.
// Block: 128 mq x 192 mk (one key image slice). Wave tile 64 x 96.
// maxv3[n][b][mt] = scale * max over this mk slice.
// ---------------------------------------------------------------------------
__global__ __launch_bounds__(256)
void scores_mfma_kernel(const __bf16* __restrict__ Qf, const __bf16* __restrict__ Kf,
                        float* __restrict__ maxv3)
{
    __shared__ __bf16 ldsQ[8192];    // 16 KB: 2 T-blocks
    __shared__ __bf16 ldsK[12288];   // 24 KB: 3 T-blocks
    __shared__ float redbuf[128][2];

    int tid = threadIdx.x, lane = tid & 63, wv = tid >> 6;
    int wq = wv >> 1, wk = wv & 1;
    int bx = blockIdx.x;                 // 0..71 (mq tile)
    int n0 = bx * 128;
    int b = blockIdx.y / 3, mt = blockIdx.y % 3;

    f32x4 acc[4][6];
#pragma unroll
    for (int ga = 0; ga < 4; ga++)
#pragma unroll
        for (int t = 0; t < 6; t++) acc[ga][t] = (f32x4){0.f, 0.f, 0.f, 0.f};

    const __bf16* qbase = Qf + (size_t)(bx * 2) * 4096;
    const __bf16* kbase = Kf + (size_t)(b * 9 + mt * 3) * 4096;

    for (int C = 0; C < 8; C++) {
        const float4* gq = (const float4*)(qbase + (size_t)C * 144 * 4096);
        const float4* gk = (const float4*)(kbase + (size_t)C * 144 * 4096);
        float4* lq = (float4*)ldsQ;
        float4* lk = (float4*)ldsK;
#pragma unroll
        for (int i = 0; i < 4; i++) lq[tid + i * 256] = gq[tid + i * 256];
#pragma unroll
        for (int i = 0; i < 6; i++) lk[tid + i * 256] = gk[tid + i * 256];
        __syncthreads();
#pragma unroll
        for (int s = 0; s < 2; s++) {
            bf16x8 af[4];
#pragma unroll
            for (int ga = 0; ga < 4; ga++)
                af[ga] = *(const bf16x8*)&ldsQ[wq * 4096 + (s * 4 + ga) * 512 + lane * 8];
#pragma unroll
            for (int t = 0; t < 6; t++) {
                int mkl = wk * 96 + t * 16;
                bf16x8 bfr = *(const bf16x8*)&ldsK[(mkl >> 6) * 4096 + (s * 4 + ((mkl >> 4) & 3)) * 512 + lane * 8];
#pragma unroll
                for (int ga = 0; ga < 4; ga++)
                    acc[ga][t] = __builtin_amdgcn_mfma_f32_16x16x32_bf16(af[ga], bfr, acc[ga][t], 0, 0, 0);
            }
        }
        __syncthreads();
    }

    // epilogue: max over mk (cols + t), keep per mq row
    float mg[4][4];
#pragma unroll
    for (int ga = 0; ga < 4; ga++)
#pragma unroll
        for (int r = 0; r < 4; r++) {
            float v = acc[ga][0][r];
#pragma unroll
            for (int t = 1; t < 6; t++) v = fmaxf(v, acc[ga][t][r]);
            mg[ga][r] = v;
        }
#pragma unroll
    for (int off = 1; off < 16; off <<= 1)
#pragma unroll
        for (int ga = 0; ga < 4; ga++)
#pragma unroll
            for (int r = 0; r < 4; r++)
                mg[ga][r] = fmaxf(mg[ga][r], __shfl_xor(mg[ga][r], off, 64));

    if ((lane & 15) == 0) {
        int quad = lane >> 4;
#pragma unroll
        for (int ga = 0; ga < 4; ga++)
#pragma unroll
            for (int r = 0; r < 4; r++)
                redbuf[wq * 64 + ga * 16 + quad * 4 + r][wk] = mg[ga][r];
    }
    __syncthreads();
    if (tid < 128) {
        float rv = fmaxf(redbuf[tid][0], redbuf[tid][1]) * SCALE;
        maxv3[((size_t)(n0 + tid) * BB + b) * 3 + mt] = rv;
    }
}

// ---------------------------------------------------------------------------
// K5: approx v per pixel (mean over b of max over mt slices), top-4 per image.
// ---------------------------------------------------------------------------
__global__ __launch_bounds__(576)
void topk_kernel(const float* __restrict__ maxv3, int* __restrict__ cand)
{
    __shared__ float sv[576];
    __shared__ float rv_[64];
    __shared__ int ri_[64];
    int bi = blockIdx.x, m = threadIdx.x;
    int n = bi * HWW + m;
    float v = 0.f;
#pragma unroll
    for (int t = 0; t < BB; t++) {
        const float* p = maxv3 + ((size_t)n * BB + t) * 3;
        v += fmaxf(fmaxf(p[0], p[1]), p[2]);
    }
    sv[m] = v;
    __syncthreads();
    for (int r = 0; r < 4; r++) {
        if (m < 64) {
            float bv = sv[m]; int bidx = m;
            for (int j = m + 64; j < 576; j += 64)
                if (sv[j] > bv) { bv = sv[j]; bidx = j; }
            rv_[m] = bv; ri_[m] = bidx;
        }
        __syncthreads();
        if (m == 0) {
            float bv = rv_[0]; int bidx = ri_[0];
            for (int j = 1; j < 64; j++)
                if (rv_[j] > bv) { bv = rv_[j]; bidx = ri_[j]; }
            cand[bi * 4 + r] = bidx;
            sv[bidx] = -3.4e38f;
        }
        __syncthreads();
    }
}

// ---------------------------------------------------------------------------
// K6: exact fp32 refinement stage 1: for each candidate, u = Kw^T q, qkb = q.kb
// ---------------------------------------------------------------------------
__global__ __launch_bounds__(256)
void refine_u_kernel(const float* __restrict__ x5, const float* __restrict__ qw,
                     const float* __restrict__ qb, const float* __restrict__ kw,
                     const float* __restrict__ kb, const int* __restrict__ cand,
                     float* __restrict__ u_all, float* __restrict__ qkbg)
{
    int cd = blockIdx.x;
    int bi = cd >> 2;
    int mstar = cand[cd];
    int tid = threadIdx.x;
    __shared__ float xcol[512], qv[512];
    xcol[tid]       = x5[(size_t)bi * CHW + tid * HWW + mstar];
    xcol[tid + 256] = x5[(size_t)bi * CHW + (tid + 256) * HWW + mstar];
    __syncthreads();
    float a0 = qb[tid], a1 = qb[tid + 256];
    for (int c2 = 0; c2 < 512; c2++) {
        float xv = xcol[c2];
        a0 = fmaf(qw[(size_t)tid * 512 + c2], xv, a0);
        a1 = fmaf(qw[(size_t)(tid + 256) * 512 + c2], xv, a1);
    }
    qv[tid] = a0; qv[tid + 256] = a1;
    __syncthreads();
    float u0 = 0.f, u1 = 0.f;
    float pk = a0 * kb[tid] + a1 * kb[tid + 256];
    for (int c = 0; c < 512; c++) {
        float qc = qv[c];
        u0 = fmaf(kw[(size_t)c * 512 + tid], qc, u0);
        u1 = fmaf(kw[(size_t)c * 512 + tid + 256], qc, u1);
    }
    u_all[(size_t)cd * 512 + tid] = u0;
    u_all[(size_t)cd * 512 + tid + 256] = u1;
    for (int off = 32; off; off >>= 1) pk += __shfl_down(pk, off, 64);
    __shared__ float pr[4];
    if ((tid & 63) == 0) pr[tid >> 6] = pk;
    __syncthreads();
    if (tid == 0) qkbg[cd] = pr[0] + pr[1] + pr[2] + pr[3];
}

// ---------------------------------------------------------------------------
// K7: refinement stage 2: maxex[cand][b'] = max_m u.x5[b',:,m]
// ---------------------------------------------------------------------------
__global__ __launch_bounds__(256)
void refine_max_kernel(const float* __restrict__ x5, const float* __restrict__ u_all,
                       float* __restrict__ maxex)
{
    int bp = blockIdx.x;     // key image
    int cg = blockIdx.y;     // candidate group of 16
    int tid = threadIdx.x;
    __shared__ float us[16 * 512];
    for (int e = tid; e < 16 * 512; e += 256) us[e] = u_all[(size_t)cg * 16 * 512 + e];
    __syncthreads();
    float a0[16], a1[16], a2[16];
#pragma unroll
    for (int j = 0; j < 16; j++) { a0[j] = 0.f; a1[j] = 0.f; a2[j] = 0.f; }
    const float* xb = x5 + (size_t)bp * CHW;
    for (int c = 0; c < 512; c++) {
        float x0 = xb[c * HWW + tid];
        float x1 = xb[c * HWW + tid + 256];
        float x2 = (tid < 64) ? xb[c * HWW + tid + 512] : 0.f;
#pragma unroll
        for (int j = 0; j < 16; j++) {
            float uc = us[j * 512 + c];
            a0[j] = fmaf(uc, x0, a0[j]);
            a1[j] = fmaf(uc, x1, a1[j]);
            a2[j] = fmaf(uc, x2, a2[j]);
        }
    }
    __shared__ float wred[16][4];
    for (int j = 0; j < 16; j++) {
        float mv = fmaxf(a0[j], a1[j]);
        if (tid < 64) mv = fmaxf(mv, a2[j]);
        for (int off = 32; off; off >>= 1) mv = fmaxf(mv, __shfl_xor(mv, off, 64));
        if ((tid & 63) == 0) wred[j][tid >> 6] = mv;
    }
    __syncthreads();
    if (tid < 16) {
        float mv = fmaxf(fmaxf(wred[tid][0], wred[tid][1]), fmaxf(wred[tid][2], wred[tid][3]));
        maxex[(size_t)(cg * 16 + tid) * BB + bp] = mv;
    }
}

// ---------------------------------------------------------------------------
// K8: pick exact argmax among candidates, write one-hot mask.
// ---------------------------------------------------------------------------
__global__ __launch_bounds__(576)
void mask_kernel(const float* __restrict__ maxex, const float* __restrict__ qkbg,
                 const int* __restrict__ cand, float* __restrict__ maskout)
{
    int bi = blockIdx.x, m = threadIdx.x;
    __shared__ float ve[4];
    __shared__ int chosen;
    if (m < 4) {
        int cd = bi * 4 + m;
        float sacc = 0.f;
#pragma unroll
        for (int t = 0; t < BB; t++) sacc += maxex[(size_t)cd * BB + t];
        ve[m] = sacc * (1.f / 16.f) + qkbg[cd];
    }
    __syncthreads();
    if (m == 0) {
        int best = 0; float bv = ve[0];
        for (int j = 1; j < 4; j++) if (ve[j] > bv) { bv = ve[j]; best = j; }
        chosen = cand[bi * 4 + best];
    }
    __syncthreads();
    maskout[bi * HWW + m] = (m == chosen) ? 1.f : 0.f;
}

// ---------------------------------------------------------------------------
// K9: inv[b,m] = 1/max(sqrt(sum_c x5^2), 1e-12)
// ---------------------------------------------------------------------------
__global__ __launch_bounds__(256)
void norm_kernel(const float* __restrict__ X5, float* __restrict__ invb)
{
    int b = blockIdx.y;
    int m0 = blockIdx.x * 64;
    int mi = threadIdx.x & 63, cs = threadIdx.x >> 6;
    float s = 0.f;
    for (int c = cs; c < CC; c += 4) {
        float x = X5[b * CHW + c * HWW + m0 + mi];
        s = fmaf(x, x, s);
    }
    __shared__ float red[4][64];
    red[cs][mi] = s;
    __syncthreads();
    if (cs == 0) {
        float t = red[0][mi] + red[1][mi] + red[2][mi] + red[3][mi];
        invb[b * HWW + m0 + mi] = 1.0f / fmaxf(sqrtf(t), 1e-12f);
    }
}

// ---------------------------------------------------------------------------
// K10: seeds[s,c] = sum_m x5[s,c,m] * inv[s,m] * mask[s,m]
// ---------------------------------------------------------------------------
__global__ __launch_bounds__(256)
void seeds_kernel(const float* __restrict__ X5, const float* __restrict__ invb,
                  const float* __restrict__ maskf, float* __restrict__ seeds)
{
    int s = blockIdx.y;
    int c = blockIdx.x * 4 + (threadIdx.x >> 6);
    int mi = threadIdx.x & 63;
    float acc = 0.f;
    for (int mt = 0; mt < 9; mt++) {
        int m = mt * 64 + mi;
        float w = invb[s * HWW + m] * maskf[s * HWW + m];
        acc = fmaf(X5[s * CHW + c * HWW + m], w, acc);
    }
    for (int off = 32; off > 0; off >>= 1) acc += __shfl_down(acc, off, 64);
    if (mi == 0) seeds[s * CC + c] = acc;
}

// ---------------------------------------------------------------------------
// K11: corr[b,m] = inv[b,m]/16 * sum_s relu( sum_c x5[b,c,m]*seeds[s,c] )
// ---------------------------------------------------------------------------
__global__ __launch_bounds__(256)
void corr_kernel(const float* __restrict__ X5, const float* __restrict__ invb,
                 const float* __restrict__ seeds, float* __restrict__ corr)
{
    __shared__ float sd[16 * 512];
    __shared__ float xs[64][65];
    __shared__ float red[4][64];
    int b = blockIdx.y;
    int m0 = blockIdx.x * 64;
    int tid = threadIdx.x;
    int mi = tid & 63, sg = tid >> 6;

    for (int e = tid; e < 16 * 512; e += 256) sd[e] = seeds[e];

    float acc[4] = {0.f, 0.f, 0.f, 0.f};
    for (int c0 = 0; c0 < CC; c0 += 64) {
        __syncthreads();
        for (int e = tid; e < 4096; e += 256) {
            int mm = e & 63, kk = e >> 6;
            xs[kk][mm] = X5[b * CHW + (c0 + kk) * HWW + m0 + mm];
        }
        __syncthreads();
#pragma unroll
        for (int kk = 0; kk < 64; kk++) {
            float xv = xs[kk][mi];
#pragma unroll
            for (int t = 0; t < 4; t++)
                acc[t] = fmaf(xv, sd[(sg * 4 + t) * CC + c0 + kk], acc[t]);
        }
    }
    float r = 0.f;
#pragma unroll
    for (int t = 0; t < 4; t++) r += fmaxf(acc[t], 0.f);
    red[sg][mi] = r;
    __syncthreads();
    if (sg == 0) {
        float tot = red[0][mi] + red[1][mi] + red[2][mi] + red[3][mi];
        corr[b * HWW + m0 + mi] = invb[b * HWW + m0 + mi] * tot * (1.0f / 16.0f);
    }
}

// ---------------------------------------------------------------------------
// K12: per-image min/max normalize of corr -> cormap
// ---------------------------------------------------------------------------
__global__ __launch_bounds__(576)
void cormap_kernel(const float* __restrict__ corr, float* __restrict__ cormap)
{
    __shared__ float sv[576];
    __shared__ float smn[64], smx[64];
    __shared__ float s_mn, s_mx;
    int b = blockIdx.x;
    int m = threadIdx.x;
    float v = corr[b * HWW + m];
    sv[m] = v;
    __syncthreads();
    if (m < 64) {
        float mn = sv[m], mx = sv[m];
        for (int j = m + 64; j < 576; j += 64) { mn = fminf(mn, sv[j]); mx = fmaxf(mx, sv[j]); }
        smn[m] = mn; smx[m] = mx;
    }
    __syncthreads();
    if (m == 0) {
        float mn = smn[0], mx = smx[0];
        for (int j = 1; j < 64; j++) { mn = fminf(mn, smn[j]); mx = fmaxf(mx, smx[j]); }
        s_mn = mn; s_mx = mx;
    }
    __syncthreads();
    cormap[b * HWW + m] = (v - s_mn) / (s_mx - s_mn + 1e-12f);
}

// ---------------------------------------------------------------------------
// K13: proto1[c] = mean_{b,m} x5[b,c,m]*cormap[b,m]
// ---------------------------------------------------------------------------
__global__ __launch_bounds__(256)
void proto_kernel(const float* __restrict__ X5, const float* __restrict__ cormap,
                  float* __restrict__ proto1)
{
    int c = blockIdx.x;
    int tid = threadIdx.x;
    float acc = 0.f;
    for (int p = tid; p < NN; p += 256) {
        int b = p / HWW, m = p % HWW;
        acc = fmaf(X5[b * CHW + c * HWW + m], cormap[p], acc);
    }
    for (int off = 32; off > 0; off >>= 1) acc += __shfl_down(acc, off, 64);
    __shared__ float red[4];
    if ((tid & 63) == 0) red[tid >> 6] = acc;
    __syncthreads();
    if (tid == 0) proto1[c] = (red[0] + red[1] + red[2] + red[3]) * (1.0f / (float)NN);
}

// ---------------------------------------------------------------------------
// K14: out3 = x5*(proto1[c] + cormap[b,m])
// ---------------------------------------------------------------------------
__global__ __launch_bounds__(256)
void final_kernel(const float* __restrict__ X5, const float* __restrict__ proto1,
                  const float* __restrict__ cormap, float* __restrict__ out3)
{
    int idx = blockIdx.x * 256 + threadIdx.x;
    if (idx >= TOT) return;
    int b = idx / CHW;
    int r = idx % CHW;
    int c = r / HWW;
    int m = r % HWW;
    float x = X5[idx];
    out3[idx] = x * (proto1[c] + cormap[b * HWW + m]);
}

// ---------------------------------------------------------------------------
extern "C" void kernel_launch(void* const* d_in, const int* in_sizes, int n_in,
                              void* d_out, int out_size, void* d_ws, size_t ws_size,
                              hipStream_t stream)
{
    const float* x  = (const float*)d_in[0];
    const float* cw = (const float*)d_in[1];
    const float* cb = (const float*)d_in[2];
    const float* qw = (const float*)d_in[3];
    const float* qb = (const float*)d_in[4];
    const float* kw = (const float*)d_in[5];
    const float* kb = (const float*)d_in[6];

    float* out     = (float*)d_out;
    float* x5o     = out;                        // output 0 (B,C,H,W)
    float* proto1  = out + TOT;                  // output 1 (512)
    float* out3    = out + TOT + 512;            // output 2 (B,C,H,W)
    float* maskout = out + TOT + 512 + TOT;      // output 3 (B,1,H,W)

    // qfrag staged inside out3's region (9.44 MB of 18.9 MB; out3 written last)
    __bf16* qfrag = (__bf16*)out3;

    char* ws = (char*)d_ws;
    __bf16* kfrag = (__bf16*)ws;                         ws += (size_t)NN * CC * sizeof(__bf16);
    float* maxv3  = (float*)ws;                          ws += (size_t)NN * BB * 3 * sizeof(float);
    int*   cand   = (int*)ws;                            ws += 64 * sizeof(int);
    float* u_all  = (float*)ws;                          ws += 64 * 512 * sizeof(float);
    float* qkbg   = (float*)ws;                          ws += 64 * sizeof(float);
    float* maxex  = (float*)ws;                          ws += 64 * BB * sizeof(float);
    float* invb   = (float*)ws;                          ws += NN * sizeof(float);
    float* corr   = (float*)ws;                          ws += NN * sizeof(float);
    float* cmap   = (float*)ws;                          ws += NN * sizeof(float);
    float* seeds  = (float*)ws;                          ws += BB * CC * sizeof(float);

    dim3 gg(NN / 64, CC / 64);
    conv1x1_res_kernel<<<gg, 256, 0, stream>>>(x, cw, cb, x5o);
    convqk_frag_kernel<<<gg, 256, 0, stream>>>(x5o, qw, qb, qfrag);
    convqk_frag_kernel<<<gg, 256, 0, stream>>>(x5o, kw, kb, kfrag);

    scores_mfma_kernel<<<dim3(NN / 128, BB * 3), 256, 0, stream>>>(qfrag, kfrag, maxv3);

    topk_kernel<<<BB, HWW, 0, stream>>>(maxv3, cand);
    refine_u_kernel<<<64, 256, 0, stream>>>(x5o, qw, qb, kw, kb, cand, u_all, qkbg);
    refine_max_kernel<<<dim3(BB, 4), 256, 0, stream>>>(x5o, u_all, maxex);
    mask_kernel<<<BB, HWW, 0, stream>>>(maxex, qkbg, cand, maskout);

    norm_kernel<<<dim3(9, BB), 256, 0, stream>>>(x5o, invb);
    seeds_kernel<<<dim3(CC / 4, BB), 256, 0, stream>>>(x5o, invb, maskout, seeds);
    corr_kernel<<<dim3(9, BB), 256, 0, stream>>>(x5o, invb, seeds, corr);
    cormap_kernel<<<BB, HWW, 0, stream>>>(corr, cmap);
    proto_kernel<<<CC, 256, 0, stream>>>(x5o, cmap, proto1);
    final_kernel<<<(TOT + 255) / 256, 256, 0, stream>>>(x5o, proto1, cmap, out3);
}

// Round 3
// 514.218 us; speedup vs baseline: 5.3003x; 1.5874x over previous
//
#include <hip/hip_runtime.h>
#include <math.h>

#define BB   16
#define CC   512
#define HWW  576
#define NN   9216            // B*HW
#define CHW  (CC*HWW)        // 294912
#define TOT  (BB*CHW)        // 4718592
#define SCALE 0.044194173824159216f  // 1/sqrt(512)
#define FRAGB 9437184        // NN*CC bf16 bytes

typedef __attribute__((ext_vector_type(8))) __bf16 bf16x8;
typedef __attribute__((ext_vector_type(4))) float f32x4;

// ---------------------------------------------------------------------------
// Fragment-linear bf16 layout (MFMA A/B operand order), 64x64 (dim,k) blocks:
//   slot(elem) = (s*4+g4)*512 + L*8 + j,  L = (q8<<4)|Lm
//   dim64 = g4*16 + Lm,   k64 = s*32 + q8*8 + j
// X/x5/q/k ("B-side", dim=pixel, k=channel): block index [Cb*144 + T]
// W ("A-side", dim=out-chan, k=in-chan):     block index [Cb*8  + To]
// Frag read for mfma_16x16x32_bf16: contiguous 16 B at lane*16.
// ---------------------------------------------------------------------------

// P1: x -> hi/lo bf16 fragment layout
__global__ __launch_bounds__(256)
void prep_x_kernel(const float* __restrict__ X, __bf16* __restrict__ Xhi,
                   __bf16* __restrict__ Xlo)
{
    int g = blockIdx.x * 256 + threadIdx.x;   // NN*64 threads
    int n = g % NN;
    int co = g / NN;                          // channel octet 0..63
    int c0 = co * 8;
    int bimg = n / HWW, mm = n % HWW;
    const float* src = X + (size_t)bimg * CHW + mm;
    union { __bf16 h[8]; float4 f4; } uh, ul;
#pragma unroll
    for (int j = 0; j < 8; j++) {
        float v = src[(size_t)(c0 + j) * HWW];
        __bf16 h = (__bf16)v;
        uh.h[j] = h;
        ul.h[j] = (__bf16)(v - (float)h);
    }
    int Cb = c0 >> 6, s = (c0 >> 5) & 1, q8 = (c0 >> 3) & 3;
    int T = n >> 6, g4 = (n >> 4) & 3, Lm = n & 15;
    size_t off = (size_t)(Cb * 144 + T) * 4096 + (s * 4 + g4) * 512 + (size_t)((q8 << 4) | Lm) * 8;
    *(float4*)&Xhi[off] = uh.f4;
    *(float4*)&Xlo[off] = ul.f4;
}

// P2: weights -> fragment layout. y=0: cw (hi+lo), y=1: qw, y=2: kw
__global__ __launch_bounds__(256)
void prep_w_kernel(const float* __restrict__ cw, const float* __restrict__ qw,
                   const float* __restrict__ kw, __bf16* __restrict__ cwhi,
                   __bf16* __restrict__ cwlo, __bf16* __restrict__ qwf,
                   __bf16* __restrict__ kwf)
{
    int y = blockIdx.y;
    const float* W = (y == 0) ? cw : (y == 1) ? qw : kw;
    __bf16* dh = (y == 0) ? cwhi : (y == 1) ? qwf : kwf;
    int g = blockIdx.x * 256 + threadIdx.x;   // 512*64 threads
    int o = g >> 6;
    int c0 = (g & 63) * 8;
    union { __bf16 h[8]; float4 f4; } uh, ul;
#pragma unroll
    for (int j = 0; j < 8; j++) {
        float v = W[(size_t)o * CC + c0 + j];
        __bf16 h = (__bf16)v;
        uh.h[j] = h;
        ul.h[j] = (__bf16)(v - (float)h);
    }
    int Cb = c0 >> 6, s = (c0 >> 5) & 1, q8 = (c0 >> 3) & 3;
    int To = o >> 6, g4 = (o >> 4) & 3, Lm = o & 15;
    size_t off = (size_t)(Cb * 8 + To) * 4096 + (s * 4 + g4) * 512 + (size_t)((q8 << 4) | Lm) * 8;
    *(float4*)&dh[off] = uh.f4;
    if (y == 0) *(float4*)&cwlo[off] = ul.f4;
}

// ---------------------------------------------------------------------------
// K1: x5 conv via hi/lo bf16 MFMA (fp32-class accuracy) + residual + bias.
// Block 128 O x 128 M, 4 waves (2x2), wave tile 64x64. Writes x5 fp32 and
// x5 bf16 fragment layout (B-operand for q/k conv).
// ---------------------------------------------------------------------------
__global__ __launch_bounds__(256)
void conv1_mfma_kernel(const float* __restrict__ X, const __bf16* __restrict__ Whi,
                       const __bf16* __restrict__ Wlo, const __bf16* __restrict__ Xhi,
                       const __bf16* __restrict__ Xlo, const float* __restrict__ bias,
                       float* __restrict__ Y, __bf16* __restrict__ Yfrag)
{
    __shared__ __bf16 lAh[8192], lAl[8192], lBh[8192], lBl[8192];
    int tid = threadIdx.x, lane = tid & 63, wv = tid >> 6;
    int wo = wv >> 1, wm = wv & 1;
    int m0 = blockIdx.x * 128;
    int o0 = blockIdx.y * 128;
    int oT0 = blockIdx.y * 2, mT0 = blockIdx.x * 2;

    f32x4 acc[4][4];
#pragma unroll
    for (int i = 0; i < 4; i++)
#pragma unroll
        for (int j = 0; j < 4; j++) acc[i][j] = (f32x4){0.f, 0.f, 0.f, 0.f};

    for (int Cb = 0; Cb < 8; Cb++) {
        const float4* gAh = (const float4*)(Whi + (size_t)(Cb * 8 + oT0) * 4096);
        const float4* gAl = (const float4*)(Wlo + (size_t)(Cb * 8 + oT0) * 4096);
        const float4* gBh = (const float4*)(Xhi + (size_t)(Cb * 144 + mT0) * 4096);
        const float4* gBl = (const float4*)(Xlo + (size_t)(Cb * 144 + mT0) * 4096);
        float4* dAh = (float4*)lAh; float4* dAl = (float4*)lAl;
        float4* dBh = (float4*)lBh; float4* dBl = (float4*)lBl;
#pragma unroll
        for (int i = 0; i < 4; i++) {
            dAh[tid + i * 256] = gAh[tid + i * 256];
            dAl[tid + i * 256] = gAl[tid + i * 256];
            dBh[tid + i * 256] = gBh[tid + i * 256];
            dBl[tid + i * 256] = gBl[tid + i * 256];
        }
        __syncthreads();
#pragma unroll
        for (int s = 0; s < 2; s++) {
            bf16x8 ah[4], al[4], bh[4], bl[4];
#pragma unroll
            for (int ga = 0; ga < 4; ga++) {
                ah[ga] = *(const bf16x8*)&lAh[wo * 4096 + (s * 4 + ga) * 512 + lane * 8];
                al[ga] = *(const bf16x8*)&lAl[wo * 4096 + (s * 4 + ga) * 512 + lane * 8];
            }
#pragma unroll
            for (int gb = 0; gb < 4; gb++) {
                bh[gb] = *(const bf16x8*)&lBh[wm * 4096 + (s * 4 + gb) * 512 + lane * 8];
                bl[gb] = *(const bf16x8*)&lBl[wm * 4096 + (s * 4 + gb) * 512 + lane * 8];
            }
#pragma unroll
            for (int ga = 0; ga < 4; ga++)
#pragma unroll
                for (int gb = 0; gb < 4; gb++) {
                    acc[ga][gb] = __builtin_amdgcn_mfma_f32_16x16x32_bf16(ah[ga], bh[gb], acc[ga][gb], 0, 0, 0);
                    acc[ga][gb] = __builtin_amdgcn_mfma_f32_16x16x32_bf16(ah[ga], bl[gb], acc[ga][gb], 0, 0, 0);
                    acc[ga][gb] = __builtin_amdgcn_mfma_f32_16x16x32_bf16(al[ga], bh[gb], acc[ga][gb], 0, 0, 0);
                }
        }
        __syncthreads();
    }

    int quad = lane >> 4, col = lane & 15;
#pragma unroll
    for (int ga = 0; ga < 4; ga++) {
        int ob = o0 + wo * 64 + ga * 16 + quad * 4;
        float bs[4];
#pragma unroll
        for (int r = 0; r < 4; r++) bs[r] = bias[ob + r];
        int Cb2 = ob >> 6, s2 = (ob >> 5) & 1, q8 = (ob >> 3) & 3, j0 = ob & 7;
#pragma unroll
        for (int gb = 0; gb < 4; gb++) {
            int n = m0 + wm * 64 + gb * 16 + col;
            int T = n >> 6, g4 = (n >> 4) & 3, Lm = n & 15;
            int bimg = n / HWW, mm = n % HWW;
            size_t xb = (size_t)bimg * CHW + mm;
            union { __bf16 h[4]; float2 f2; } u;
#pragma unroll
            for (int r = 0; r < 4; r++) {
                float v = acc[ga][gb][r] + bs[r] + X[xb + (size_t)(ob + r) * HWW];
                Y[xb + (size_t)(ob + r) * HWW] = v;
                u.h[r] = (__bf16)v;
            }
            *(float2*)&Yfrag[(size_t)(Cb2 * 144 + T) * 4096 + (s2 * 4 + g4) * 512 + (size_t)((q8 << 4) | Lm) * 8 + j0] = u.f2;
        }
    }
}

// ---------------------------------------------------------------------------
// K2: q & k convs via plain bf16 MFMA from x5 fragment layout.
// blockIdx.z: 0 -> q, 1 -> k. Output: bf16 fragment layout.
// ---------------------------------------------------------------------------
__global__ __launch_bounds__(256)
void convqk_mfma_kernel(const __bf16* __restrict__ qwf, const __bf16* __restrict__ kwf,
                        const float* __restrict__ qb, const float* __restrict__ kb,
                        const __bf16* __restrict__ Xf, __bf16* __restrict__ Oq,
                        __bf16* __restrict__ Ok)
{
    const __bf16* Wf = blockIdx.z ? kwf : qwf;
    const float* bias = blockIdx.z ? kb : qb;
    __bf16* Of = blockIdx.z ? Ok : Oq;

    __shared__ __bf16 lA[8192], lB[8192];
    int tid = threadIdx.x, lane = tid & 63, wv = tid >> 6;
    int wo = wv >> 1, wm = wv & 1;
    int m0 = blockIdx.x * 128;
    int o0 = blockIdx.y * 128;
    int oT0 = blockIdx.y * 2, mT0 = blockIdx.x * 2;

    f32x4 acc[4][4];
#pragma unroll
    for (int i = 0; i < 4; i++)
#pragma unroll
        for (int j = 0; j < 4; j++) acc[i][j] = (f32x4){0.f, 0.f, 0.f, 0.f};

    for (int Cb = 0; Cb < 8; Cb++) {
        const float4* gA = (const float4*)(Wf + (size_t)(Cb * 8 + oT0) * 4096);
        const float4* gB = (const float4*)(Xf + (size_t)(Cb * 144 + mT0) * 4096);
        float4* dA = (float4*)lA; float4* dB = (float4*)lB;
#pragma unroll
        for (int i = 0; i < 4; i++) {
            dA[tid + i * 256] = gA[tid + i * 256];
            dB[tid + i * 256] = gB[tid + i * 256];
        }
        __syncthreads();
#pragma unroll
        for (int s = 0; s < 2; s++) {
            bf16x8 af[4], bf[4];
#pragma unroll
            for (int ga = 0; ga < 4; ga++)
                af[ga] = *(const bf16x8*)&lA[wo * 4096 + (s * 4 + ga) * 512 + lane * 8];
#pragma unroll
            for (int gb = 0; gb < 4; gb++)
                bf[gb] = *(const bf16x8*)&lB[wm * 4096 + (s * 4 + gb) * 512 + lane * 8];
#pragma unroll
            for (int ga = 0; ga < 4; ga++)
#pragma unroll
                for (int gb = 0; gb < 4; gb++)
                    acc[ga][gb] = __builtin_amdgcn_mfma_f32_16x16x32_bf16(af[ga], bf[gb], acc[ga][gb], 0, 0, 0);
        }
        __syncthreads();
    }

    int quad = lane >> 4, col = lane & 15;
#pragma unroll
    for (int ga = 0; ga < 4; ga++) {
        int ob = o0 + wo * 64 + ga * 16 + quad * 4;
        float bs[4];
#pragma unroll
        for (int r = 0; r < 4; r++) bs[r] = bias[ob + r];
        int Cb2 = ob >> 6, s2 = (ob >> 5) & 1, q8 = (ob >> 3) & 3, j0 = ob & 7;
#pragma unroll
        for (int gb = 0; gb < 4; gb++) {
            int n = m0 + wm * 64 + gb * 16 + col;
            int T = n >> 6, g4 = (n >> 4) & 3, Lm = n & 15;
            union { __bf16 h[4]; float2 f2; } u;
#pragma unroll
            for (int r = 0; r < 4; r++) u.h[r] = (__bf16)(acc[ga][gb][r] + bs[r]);
            *(float2*)&Of[(size_t)(Cb2 * 144 + T) * 4096 + (s2 * 4 + g4) * 512 + (size_t)((q8 << 4) | Lm) * 8 + j0] = u.f2;
        }
    }
}

// ---------------------------------------------------------------------------
// K4: scores GEMM on MFMA (bf16) + max over key locations. (unchanged)
// ---------------------------------------------------------------------------
__global__ __launch_bounds__(256)
void scores_mfma_kernel(const __bf16* __restrict__ Qf, const __bf16* __restrict__ Kf,
                        float* __restrict__ maxv3)
{
    __shared__ __bf16 ldsQ[8192];
    __shared__ __bf16 ldsK[12288];
    __shared__ float redbuf[128][2];

    int tid = threadIdx.x, lane = tid & 63, wv = tid >> 6;
    int wq = wv >> 1, wk = wv & 1;
    int bx = blockIdx.x;
    int n0 = bx * 128;
    int b = blockIdx.y / 3, mt = blockIdx.y % 3;

    f32x4 acc[4][6];
#pragma unroll
    for (int ga = 0; ga < 4; ga++)
#pragma unroll
        for (int t = 0; t < 6; t++) acc[ga][t] = (f32x4){0.f, 0.f, 0.f, 0.f};

    const __bf16* qbase = Qf + (size_t)(bx * 2) * 4096;
    const __bf16* kbase = Kf + (size_t)(b * 9 + mt * 3) * 4096;

    for (int C = 0; C < 8; C++) {
        const float4* gq = (const float4*)(qbase + (size_t)C * 144 * 4096);
        const float4* gk = (const float4*)(kbase + (size_t)C * 144 * 4096);
        float4* lq = (float4*)ldsQ;
        float4* lk = (float4*)ldsK;
#pragma unroll
        for (int i = 0; i < 4; i++) lq[tid + i * 256] = gq[tid + i * 256];
#pragma unroll
        for (int i = 0; i < 6; i++) lk[tid + i * 256] = gk[tid + i * 256];
        __syncthreads();
#pragma unroll
        for (int s = 0; s < 2; s++) {
            bf16x8 af[4];
#pragma unroll
            for (int ga = 0; ga < 4; ga++)
                af[ga] = *(const bf16x8*)&ldsQ[wq * 4096 + (s * 4 + ga) * 512 + lane * 8];
#pragma unroll
            for (int t = 0; t < 6; t++) {
                int mkl = wk * 96 + t * 16;
                bf16x8 bfr = *(const bf16x8*)&ldsK[(mkl >> 6) * 4096 + (s * 4 + ((mkl >> 4) & 3)) * 512 + lane * 8];
#pragma unroll
                for (int ga = 0; ga < 4; ga++)
                    acc[ga][t] = __builtin_amdgcn_mfma_f32_16x16x32_bf16(af[ga], bfr, acc[ga][t], 0, 0, 0);
            }
        }
        __syncthreads();
    }

    float mg[4][4];
#pragma unroll
    for (int ga = 0; ga < 4; ga++)
#pragma unroll
        for (int r = 0; r < 4; r++) {
            float v = acc[ga][0][r];
#pragma unroll
            for (int t = 1; t < 6; t++) v = fmaxf(v, acc[ga][t][r]);
            mg[ga][r] = v;
        }
#pragma unroll
    for (int off = 1; off < 16; off <<= 1)
#pragma unroll
        for (int ga = 0; ga < 4; ga++)
#pragma unroll
            for (int r = 0; r < 4; r++)
                mg[ga][r] = fmaxf(mg[ga][r], __shfl_xor(mg[ga][r], off, 64));

    if ((lane & 15) == 0) {
        int quad = lane >> 4;
#pragma unroll
        for (int ga = 0; ga < 4; ga++)
#pragma unroll
            for (int r = 0; r < 4; r++)
                redbuf[wq * 64 + ga * 16 + quad * 4 + r][wk] = mg[ga][r];
    }
    __syncthreads();
    if (tid < 128) {
        float rv = fmaxf(redbuf[tid][0], redbuf[tid][1]) * SCALE;
        maxv3[((size_t)(n0 + tid) * BB + b) * 3 + mt] = rv;
    }
}

// ---------------------------------------------------------------------------
// K5: approx v, top-4 candidates per image. (unchanged)
// ---------------------------------------------------------------------------
__global__ __launch_bounds__(576)
void topk_kernel(const float* __restrict__ maxv3, int* __restrict__ cand)
{
    __shared__ float sv[576];
    __shared__ float rv_[64];
    __shared__ int ri_[64];
    int bi = blockIdx.x, m = threadIdx.x;
    int n = bi * HWW + m;
    float v = 0.f;
#pragma unroll
    for (int t = 0; t < BB; t++) {
        const float* p = maxv3 + ((size_t)n * BB + t) * 3;
        v += fmaxf(fmaxf(p[0], p[1]), p[2]);
    }
    sv[m] = v;
    __syncthreads();
    for (int r = 0; r < 4; r++) {
        if (m < 64) {
            float bv = sv[m]; int bidx = m;
            for (int j = m + 64; j < 576; j += 64)
                if (sv[j] > bv) { bv = sv[j]; bidx = j; }
            rv_[m] = bv; ri_[m] = bidx;
        }
        __syncthreads();
        if (m == 0) {
            float bv = rv_[0]; int bidx = ri_[0];
            for (int j = 1; j < 64; j++)
                if (rv_[j] > bv) { bv = rv_[j]; bidx = ri_[j]; }
            cand[bi * 4 + r] = bidx;
            sv[bidx] = -3.4e38f;
        }
        __syncthreads();
    }
}

// ---------------------------------------------------------------------------
// K6: exact fp32 refinement stage 1 (unchanged)
// ---------------------------------------------------------------------------
__global__ __launch_bounds__(256)
void refine_u_kernel(const float* __restrict__ x5, const float* __restrict__ qw,
                     const float* __restrict__ qb, const float* __restrict__ kw,
                     const float* __restrict__ kb, const int* __restrict__ cand,
                     float* __restrict__ u_all, float* __restrict__ qkbg)
{
    int cd = blockIdx.x;
    int bi = cd >> 2;
    int mstar = cand[cd];
    int tid = threadIdx.x;
    __shared__ float xcol[512], qv[512];
    xcol[tid]       = x5[(size_t)bi * CHW + tid * HWW + mstar];
    xcol[tid + 256] = x5[(size_t)bi * CHW + (tid + 256) * HWW + mstar];
    __syncthreads();
    float a0 = qb[tid], a1 = qb[tid + 256];
    for (int c2 = 0; c2 < 512; c2++) {
        float xv = xcol[c2];
        a0 = fmaf(qw[(size_t)tid * 512 + c2], xv, a0);
        a1 = fmaf(qw[(size_t)(tid + 256) * 512 + c2], xv, a1);
    }
    qv[tid] = a0; qv[tid + 256] = a1;
    __syncthreads();
    float u0 = 0.f, u1 = 0.f;
    float pk = a0 * kb[tid] + a1 * kb[tid + 256];
    for (int c = 0; c < 512; c++) {
        float qc = qv[c];
        u0 = fmaf(kw[(size_t)c * 512 + tid], qc, u0);
        u1 = fmaf(kw[(size_t)c * 512 + tid + 256], qc, u1);
    }
    u_all[(size_t)cd * 512 + tid] = u0;
    u_all[(size_t)cd * 512 + tid + 256] = u1;
    for (int off = 32; off; off >>= 1) pk += __shfl_down(pk, off, 64);
    __shared__ float pr[4];
    if ((tid & 63) == 0) pr[tid >> 6] = pk;
    __syncthreads();
    if (tid == 0) qkbg[cd] = pr[0] + pr[1] + pr[2] + pr[3];
}

// ---------------------------------------------------------------------------
// K7: refinement stage 2 (unchanged)
// ---------------------------------------------------------------------------
__global__ __launch_bounds__(256)
void refine_max_kernel(const float* __restrict__ x5, const float* __restrict__ u_all,
                       float* __restrict__ maxex)
{
    int bp = blockIdx.x;
    int cg = blockIdx.y;
    int tid = threadIdx.x;
    __shared__ float us[16 * 512];
    for (int e = tid; e < 16 * 512; e += 256) us[e] = u_all[(size_t)cg * 16 * 512 + e];
    __syncthreads();
    float a0[16], a1[16], a2[16];
#pragma unroll
    for (int j = 0; j < 16; j++) { a0[j] = 0.f; a1[j] = 0.f; a2[j] = 0.f; }
    const float* xb = x5 + (size_t)bp * CHW;
    for (int c = 0; c < 512; c++) {
        float x0 = xb[c * HWW + tid];
        float x1 = xb[c * HWW + tid + 256];
        float x2 = (tid < 64) ? xb[c * HWW + tid + 512] : 0.f;
#pragma unroll
        for (int j = 0; j < 16; j++) {
            float uc = us[j * 512 + c];
            a0[j] = fmaf(uc, x0, a0[j]);
            a1[j] = fmaf(uc, x1, a1[j]);
            a2[j] = fmaf(uc, x2, a2[j]);
        }
    }
    __shared__ float wred[16][4];
    for (int j = 0; j < 16; j++) {
        float mv = fmaxf(a0[j], a1[j]);
        if (tid < 64) mv = fmaxf(mv, a2[j]);
        for (int off = 32; off; off >>= 1) mv = fmaxf(mv, __shfl_xor(mv, off, 64));
        if ((tid & 63) == 0) wred[j][tid >> 6] = mv;
    }
    __syncthreads();
    if (tid < 16) {
        float mv = fmaxf(fmaxf(wred[tid][0], wred[tid][1]), fmaxf(wred[tid][2], wred[tid][3]));
        maxex[(size_t)(cg * 16 + tid) * BB + bp] = mv;
    }
}

// ---------------------------------------------------------------------------
// K8: exact argmax among candidates -> one-hot mask (unchanged)
// ---------------------------------------------------------------------------
__global__ __launch_bounds__(576)
void mask_kernel(const float* __restrict__ maxex, const float* __restrict__ qkbg,
                 const int* __restrict__ cand, float* __restrict__ maskout)
{
    int bi = blockIdx.x, m = threadIdx.x;
    __shared__ float ve[4];
    __shared__ int chosen;
    if (m < 4) {
        int cd = bi * 4 + m;
        float sacc = 0.f;
#pragma unroll
        for (int t = 0; t < BB; t++) sacc += maxex[(size_t)cd * BB + t];
        ve[m] = sacc * (1.f / 16.f) + qkbg[cd];
    }
    __syncthreads();
    if (m == 0) {
        int best = 0; float bv = ve[0];
        for (int j = 1; j < 4; j++) if (ve[j] > bv) { bv = ve[j]; best = j; }
        chosen = cand[bi * 4 + best];
    }
    __syncthreads();
    maskout[bi * HWW + m] = (m == chosen) ? 1.f : 0.f;
}

// ---------------------------------------------------------------------------
// K9..K14: unchanged fp32 tail
// ---------------------------------------------------------------------------
__global__ __launch_bounds__(256)
void norm_kernel(const float* __restrict__ X5, float* __restrict__ invb)
{
    int b = blockIdx.y;
    int m0 = blockIdx.x * 64;
    int mi = threadIdx.x & 63, cs = threadIdx.x >> 6;
    float s = 0.f;
    for (int c = cs; c < CC; c += 4) {
        float x = X5[b * CHW + c * HWW + m0 + mi];
        s = fmaf(x, x, s);
    }
    __shared__ float red[4][64];
    red[cs][mi] = s;
    __syncthreads();
    if (cs == 0) {
        float t = red[0][mi] + red[1][mi] + red[2][mi] + red[3][mi];
        invb[b * HWW + m0 + mi] = 1.0f / fmaxf(sqrtf(t), 1e-12f);
    }
}

__global__ __launch_bounds__(256)
void seeds_kernel(const float* __restrict__ X5, const float* __restrict__ invb,
                  const float* __restrict__ maskf, float* __restrict__ seeds)
{
    int s = blockIdx.y;
    int c = blockIdx.x * 4 + (threadIdx.x >> 6);
    int mi = threadIdx.x & 63;
    float acc = 0.f;
    for (int mt = 0; mt < 9; mt++) {
        int m = mt * 64 + mi;
        float w = invb[s * HWW + m] * maskf[s * HWW + m];
        acc = fmaf(X5[s * CHW + c * HWW + m], w, acc);
    }
    for (int off = 32; off > 0; off >>= 1) acc += __shfl_down(acc, off, 64);
    if (mi == 0) seeds[s * CC + c] = acc;
}

__global__ __launch_bounds__(256)
void corr_kernel(const float* __restrict__ X5, const float* __restrict__ invb,
                 const float* __restrict__ seeds, float* __restrict__ corr)
{
    __shared__ float sd[16 * 512];
    __shared__ float xs[64][65];
    __shared__ float red[4][64];
    int b = blockIdx.y;
    int m0 = blockIdx.x * 64;
    int tid = threadIdx.x;
    int mi = tid & 63, sg = tid >> 6;

    for (int e = tid; e < 16 * 512; e += 256) sd[e] = seeds[e];

    float acc[4] = {0.f, 0.f, 0.f, 0.f};
    for (int c0 = 0; c0 < CC; c0 += 64) {
        __syncthreads();
        for (int e = tid; e < 4096; e += 256) {
            int mm = e & 63, kk = e >> 6;
            xs[kk][mm] = X5[b * CHW + (c0 + kk) * HWW + m0 + mm];
        }
        __syncthreads();
#pragma unroll
        for (int kk = 0; kk < 64; kk++) {
            float xv = xs[kk][mi];
#pragma unroll
            for (int t = 0; t < 4; t++)
                acc[t] = fmaf(xv, sd[(sg * 4 + t) * CC + c0 + kk], acc[t]);
        }
    }
    float r = 0.f;
#pragma unroll
    for (int t = 0; t < 4; t++) r += fmaxf(acc[t], 0.f);
    red[sg][mi] = r;
    __syncthreads();
    if (sg == 0) {
        float tot = red[0][mi] + red[1][mi] + red[2][mi] + red[3][mi];
        corr[b * HWW + m0 + mi] = invb[b * HWW + m0 + mi] * tot * (1.0f / 16.0f);
    }
}

__global__ __launch_bounds__(576)
void cormap_kernel(const float* __restrict__ corr, float* __restrict__ cormap)
{
    __shared__ float sv[576];
    __shared__ float smn[64], smx[64];
    __shared__ float s_mn, s_mx;
    int b = blockIdx.x;
    int m = threadIdx.x;
    float v = corr[b * HWW + m];
    sv[m] = v;
    __syncthreads();
    if (m < 64) {
        float mn = sv[m], mx = sv[m];
        for (int j = m + 64; j < 576; j += 64) { mn = fminf(mn, sv[j]); mx = fmaxf(mx, sv[j]); }
        smn[m] = mn; smx[m] = mx;
    }
    __syncthreads();
    if (m == 0) {
        float mn = smn[0], mx = smx[0];
        for (int j = 1; j < 64; j++) { mn = fminf(mn, smn[j]); mx = fmaxf(mx, smx[j]); }
        s_mn = mn; s_mx = mx;
    }
    __syncthreads();
    cormap[b * HWW + m] = (v - s_mn) / (s_mx - s_mn + 1e-12f);
}

__global__ __launch_bounds__(256)
void proto_kernel(const float* __restrict__ X5, const float* __restrict__ cormap,
                  float* __restrict__ proto1)
{
    int c = blockIdx.x;
    int tid = threadIdx.x;
    float acc = 0.f;
    for (int p = tid; p < NN; p += 256) {
        int b = p / HWW, m = p % HWW;
        acc = fmaf(X5[b * CHW + c * HWW + m], cormap[p], acc);
    }
    for (int off = 32; off > 0; off >>= 1) acc += __shfl_down(acc, off, 64);
    __shared__ float red[4];
    if ((tid & 63) == 0) red[tid >> 6] = acc;
    __syncthreads();
    if (tid == 0) proto1[c] = (red[0] + red[1] + red[2] + red[3]) * (1.0f / (float)NN);
}

__global__ __launch_bounds__(256)
void final_kernel(const float* __restrict__ X5, const float* __restrict__ proto1,
                  const float* __restrict__ cormap, float* __restrict__ out3)
{
    int idx = blockIdx.x * 256 + threadIdx.x;
    if (idx >= TOT) return;
    int b = idx / CHW;
    int r = idx % CHW;
    int c = r / HWW;
    int m = r % HWW;
    float x = X5[idx];
    out3[idx] = x * (proto1[c] + cormap[b * HWW + m]);
}

// ---------------------------------------------------------------------------
extern "C" void kernel_launch(void* const* d_in, const int* in_sizes, int n_in,
                              void* d_out, int out_size, void* d_ws, size_t ws_size,
                              hipStream_t stream)
{
    const float* x  = (const float*)d_in[0];
    const float* cw = (const float*)d_in[1];
    const float* cb = (const float*)d_in[2];
    const float* qw = (const float*)d_in[3];
    const float* qb = (const float*)d_in[4];
    const float* kw = (const float*)d_in[5];
    const float* kb = (const float*)d_in[6];

    float* out     = (float*)d_out;
    float* x5o     = out;                        // output 0
    float* proto1  = out + TOT;                  // output 1
    float* out3    = out + TOT + 512;            // output 2
    float* maskout = out + TOT + 512 + TOT;      // output 3

    // out3 region overlays (all consumed before final_kernel writes out3):
    //   [0, 9.44MB):      xlo  -> later qfrag
    //   [9.44MB, 18.9MB): x5frag
    char* o3 = (char*)out3;
    __bf16* xlo    = (__bf16*)o3;
    __bf16* qfrag  = (__bf16*)o3;                // overwrites xlo after conv1
    __bf16* x5frag = (__bf16*)(o3 + FRAGB);

    // ws layout:
    char* ws = (char*)d_ws;
    __bf16* xhi   = (__bf16*)ws;                 // -> later kfrag (same slot)
    __bf16* kfrag = (__bf16*)ws;
    __bf16* cwhi  = (__bf16*)(ws + FRAGB);
    __bf16* cwlo  = (__bf16*)(ws + FRAGB + 524288);
    __bf16* qwf   = (__bf16*)(ws + FRAGB + 2 * 524288);
    __bf16* kwf   = (__bf16*)(ws + FRAGB + 3 * 524288);
    char* p = ws + FRAGB + 4 * 524288;
    float* maxv3  = (float*)p;   p += (size_t)NN * BB * 3 * 4;
    int*   cand   = (int*)p;     p += 256;
    float* u_all  = (float*)p;   p += 64 * 512 * 4;
    float* qkbg   = (float*)p;   p += 256;
    float* maxex  = (float*)p;   p += 64 * BB * 4;
    float* invb   = (float*)p;   p += NN * 4;
    float* corr   = (float*)p;   p += NN * 4;
    float* cmap   = (float*)p;   p += NN * 4;
    float* seeds  = (float*)p;   p += BB * CC * 4;

    prep_x_kernel<<<NN * 64 / 256, 256, 0, stream>>>(x, xhi, xlo);
    prep_w_kernel<<<dim3(128, 3), 256, 0, stream>>>(cw, qw, kw, cwhi, cwlo, qwf, kwf);

    conv1_mfma_kernel<<<dim3(NN / 128, 4), 256, 0, stream>>>(x, cwhi, cwlo, xhi, xlo, cb, x5o, x5frag);
    convqk_mfma_kernel<<<dim3(NN / 128, 4, 2), 256, 0, stream>>>(qwf, kwf, qb, kb, x5frag, qfrag, kfrag);

    scores_mfma_kernel<<<dim3(NN / 128, BB * 3), 256, 0, stream>>>(qfrag, kfrag, maxv3);

    topk_kernel<<<BB, HWW, 0, stream>>>(maxv3, cand);
    refine_u_kernel<<<64, 256, 0, stream>>>(x5o, qw, qb, kw, kb, cand, u_all, qkbg);
    refine_max_kernel<<<dim3(BB, 4), 256, 0, stream>>>(x5o, u_all, maxex);
    mask_kernel<<<BB, HWW, 0, stream>>>(maxex, qkbg, cand, maskout);

    norm_kernel<<<dim3(9, BB), 256, 0, stream>>>(x5o, invb);
    seeds_kernel<<<dim3(CC / 4, BB), 256, 0, stream>>>(x5o, invb, maskout, seeds);
    corr_kernel<<<dim3(9, BB), 256, 0, stream>>>(x5o, invb, seeds, corr);
    cormap_kernel<<<BB, HWW, 0, stream>>>(corr, cmap);
    proto_kernel<<<CC, 256, 0, stream>>>(x5o, cmap, proto1);
    final_kernel<<<(TOT + 255) / 256, 256, 0, stream>>>(x5o, proto1, cmap, out3);
}

// Round 4
// 420.428 us; speedup vs baseline: 6.4827x; 1.2231x over previous
//
#include <hip/hip_runtime.h>
#include <math.h>

#define BB   16
#define CC   512
#define HWW  576
#define NN   9216            // B*HW
#define CHW  (CC*HWW)        // 294912
#define TOT  (BB*CHW)        // 4718592
#define SCALE 0.044194173824159216f  // 1/sqrt(512)
#define FRAGB 9437184        // NN*CC bf16 bytes

typedef __attribute__((ext_vector_type(8))) __bf16 bf16x8;
typedef __attribute__((ext_vector_type(4))) float f32x4;

// ---------------------------------------------------------------------------
// Fragment-linear bf16 layout (MFMA A/B operand order), 64x64 (dim,k) blocks:
//   slot(elem) = (s*4+g4)*512 + L*8 + j,  L = (q8<<4)|Lm
//   dim64 = g4*16 + Lm,   k64 = s*32 + q8*8 + j
// X/x5/q/k ("B-side", dim=pixel, k=channel): block index [Cb*144 + T]
// W ("A-side", dim=out-chan, k=in-chan):     block index [Cb*8  + To]
// Frag read for mfma_16x16x32_bf16: contiguous 16 B at lane*16.
// ---------------------------------------------------------------------------

// P1: x -> hi/lo bf16 fragment layout
__global__ __launch_bounds__(256)
void prep_x_kernel(const float* __restrict__ X, __bf16* __restrict__ Xhi,
                   __bf16* __restrict__ Xlo)
{
    int g = blockIdx.x * 256 + threadIdx.x;   // NN*64 threads
    int n = g % NN;
    int co = g / NN;                          // channel octet 0..63
    int c0 = co * 8;
    int bimg = n / HWW, mm = n % HWW;
    const float* src = X + (size_t)bimg * CHW + mm;
    union { __bf16 h[8]; float4 f4; } uh, ul;
#pragma unroll
    for (int j = 0; j < 8; j++) {
        float v = src[(size_t)(c0 + j) * HWW];
        __bf16 h = (__bf16)v;
        uh.h[j] = h;
        ul.h[j] = (__bf16)(v - (float)h);
    }
    int Cb = c0 >> 6, s = (c0 >> 5) & 1, q8 = (c0 >> 3) & 3;
    int T = n >> 6, g4 = (n >> 4) & 3, Lm = n & 15;
    size_t off = (size_t)(Cb * 144 + T) * 4096 + (s * 4 + g4) * 512 + (size_t)((q8 << 4) | Lm) * 8;
    *(float4*)&Xhi[off] = uh.f4;
    *(float4*)&Xlo[off] = ul.f4;
}

// P2: weights -> fragment layout. y=0: cw (hi+lo), y=1: qw, y=2: kw
__global__ __launch_bounds__(256)
void prep_w_kernel(const float* __restrict__ cw, const float* __restrict__ qw,
                   const float* __restrict__ kw, __bf16* __restrict__ cwhi,
                   __bf16* __restrict__ cwlo, __bf16* __restrict__ qwf,
                   __bf16* __restrict__ kwf)
{
    int y = blockIdx.y;
    const float* W = (y == 0) ? cw : (y == 1) ? qw : kw;
    __bf16* dh = (y == 0) ? cwhi : (y == 1) ? qwf : kwf;
    int g = blockIdx.x * 256 + threadIdx.x;   // 512*64 threads
    int o = g >> 6;
    int c0 = (g & 63) * 8;
    union { __bf16 h[8]; float4 f4; } uh, ul;
#pragma unroll
    for (int j = 0; j < 8; j++) {
        float v = W[(size_t)o * CC + c0 + j];
        __bf16 h = (__bf16)v;
        uh.h[j] = h;
        ul.h[j] = (__bf16)(v - (float)h);
    }
    int Cb = c0 >> 6, s = (c0 >> 5) & 1, q8 = (c0 >> 3) & 3;
    int To = o >> 6, g4 = (o >> 4) & 3, Lm = o & 15;
    size_t off = (size_t)(Cb * 8 + To) * 4096 + (s * 4 + g4) * 512 + (size_t)((q8 << 4) | Lm) * 8;
    *(float4*)&dh[off] = uh.f4;
    if (y == 0) *(float4*)&cwlo[off] = ul.f4;
}

// ---------------------------------------------------------------------------
// K1: x5 conv via hi/lo bf16 MFMA (fp32-class accuracy) + residual + bias.
// ---------------------------------------------------------------------------
__global__ __launch_bounds__(256)
void conv1_mfma_kernel(const float* __restrict__ X, const __bf16* __restrict__ Whi,
                       const __bf16* __restrict__ Wlo, const __bf16* __restrict__ Xhi,
                       const __bf16* __restrict__ Xlo, const float* __restrict__ bias,
                       float* __restrict__ Y, __bf16* __restrict__ Yfrag)
{
    __shared__ __bf16 lAh[8192], lAl[8192], lBh[8192], lBl[8192];
    int tid = threadIdx.x, lane = tid & 63, wv = tid >> 6;
    int wo = wv >> 1, wm = wv & 1;
    int m0 = blockIdx.x * 128;
    int o0 = blockIdx.y * 128;
    int oT0 = blockIdx.y * 2, mT0 = blockIdx.x * 2;

    f32x4 acc[4][4];
#pragma unroll
    for (int i = 0; i < 4; i++)
#pragma unroll
        for (int j = 0; j < 4; j++) acc[i][j] = (f32x4){0.f, 0.f, 0.f, 0.f};

    for (int Cb = 0; Cb < 8; Cb++) {
        const float4* gAh = (const float4*)(Whi + (size_t)(Cb * 8 + oT0) * 4096);
        const float4* gAl = (const float4*)(Wlo + (size_t)(Cb * 8 + oT0) * 4096);
        const float4* gBh = (const float4*)(Xhi + (size_t)(Cb * 144 + mT0) * 4096);
        const float4* gBl = (const float4*)(Xlo + (size_t)(Cb * 144 + mT0) * 4096);
        float4* dAh = (float4*)lAh; float4* dAl = (float4*)lAl;
        float4* dBh = (float4*)lBh; float4* dBl = (float4*)lBl;
#pragma unroll
        for (int i = 0; i < 4; i++) {
            dAh[tid + i * 256] = gAh[tid + i * 256];
            dAl[tid + i * 256] = gAl[tid + i * 256];
            dBh[tid + i * 256] = gBh[tid + i * 256];
            dBl[tid + i * 256] = gBl[tid + i * 256];
        }
        __syncthreads();
#pragma unroll
        for (int s = 0; s < 2; s++) {
            bf16x8 ah[4], al[4], bh[4], bl[4];
#pragma unroll
            for (int ga = 0; ga < 4; ga++) {
                ah[ga] = *(const bf16x8*)&lAh[wo * 4096 + (s * 4 + ga) * 512 + lane * 8];
                al[ga] = *(const bf16x8*)&lAl[wo * 4096 + (s * 4 + ga) * 512 + lane * 8];
            }
#pragma unroll
            for (int gb = 0; gb < 4; gb++) {
                bh[gb] = *(const bf16x8*)&lBh[wm * 4096 + (s * 4 + gb) * 512 + lane * 8];
                bl[gb] = *(const bf16x8*)&lBl[wm * 4096 + (s * 4 + gb) * 512 + lane * 8];
            }
#pragma unroll
            for (int ga = 0; ga < 4; ga++)
#pragma unroll
                for (int gb = 0; gb < 4; gb++) {
                    acc[ga][gb] = __builtin_amdgcn_mfma_f32_16x16x32_bf16(ah[ga], bh[gb], acc[ga][gb], 0, 0, 0);
                    acc[ga][gb] = __builtin_amdgcn_mfma_f32_16x16x32_bf16(ah[ga], bl[gb], acc[ga][gb], 0, 0, 0);
                    acc[ga][gb] = __builtin_amdgcn_mfma_f32_16x16x32_bf16(al[ga], bh[gb], acc[ga][gb], 0, 0, 0);
                }
        }
        __syncthreads();
    }

    int quad = lane >> 4, col = lane & 15;
#pragma unroll
    for (int ga = 0; ga < 4; ga++) {
        int ob = o0 + wo * 64 + ga * 16 + quad * 4;
        float bs[4];
#pragma unroll
        for (int r = 0; r < 4; r++) bs[r] = bias[ob + r];
        int Cb2 = ob >> 6, s2 = (ob >> 5) & 1, q8 = (ob >> 3) & 3, j0 = ob & 7;
#pragma unroll
        for (int gb = 0; gb < 4; gb++) {
            int n = m0 + wm * 64 + gb * 16 + col;
            int T = n >> 6, g4 = (n >> 4) & 3, Lm = n & 15;
            int bimg = n / HWW, mm = n % HWW;
            size_t xb = (size_t)bimg * CHW + mm;
            union { __bf16 h[4]; float2 f2; } u;
#pragma unroll
            for (int r = 0; r < 4; r++) {
                float v = acc[ga][gb][r] + bs[r] + X[xb + (size_t)(ob + r) * HWW];
                Y[xb + (size_t)(ob + r) * HWW] = v;
                u.h[r] = (__bf16)v;
            }
            *(float2*)&Yfrag[(size_t)(Cb2 * 144 + T) * 4096 + (s2 * 4 + g4) * 512 + (size_t)((q8 << 4) | Lm) * 8 + j0] = u.f2;
        }
    }
}

// ---------------------------------------------------------------------------
// K2: q & k convs via plain bf16 MFMA from x5 fragment layout.
// ---------------------------------------------------------------------------
__global__ __launch_bounds__(256)
void convqk_mfma_kernel(const __bf16* __restrict__ qwf, const __bf16* __restrict__ kwf,
                        const float* __restrict__ qb, const float* __restrict__ kb,
                        const __bf16* __restrict__ Xf, __bf16* __restrict__ Oq,
                        __bf16* __restrict__ Ok)
{
    const __bf16* Wf = blockIdx.z ? kwf : qwf;
    const float* bias = blockIdx.z ? kb : qb;
    __bf16* Of = blockIdx.z ? Ok : Oq;

    __shared__ __bf16 lA[8192], lB[8192];
    int tid = threadIdx.x, lane = tid & 63, wv = tid >> 6;
    int wo = wv >> 1, wm = wv & 1;
    int m0 = blockIdx.x * 128;
    int o0 = blockIdx.y * 128;
    int oT0 = blockIdx.y * 2, mT0 = blockIdx.x * 2;

    f32x4 acc[4][4];
#pragma unroll
    for (int i = 0; i < 4; i++)
#pragma unroll
        for (int j = 0; j < 4; j++) acc[i][j] = (f32x4){0.f, 0.f, 0.f, 0.f};

    for (int Cb = 0; Cb < 8; Cb++) {
        const float4* gA = (const float4*)(Wf + (size_t)(Cb * 8 + oT0) * 4096);
        const float4* gB = (const float4*)(Xf + (size_t)(Cb * 144 + mT0) * 4096);
        float4* dA = (float4*)lA; float4* dB = (float4*)lB;
#pragma unroll
        for (int i = 0; i < 4; i++) {
            dA[tid + i * 256] = gA[tid + i * 256];
            dB[tid + i * 256] = gB[tid + i * 256];
        }
        __syncthreads();
#pragma unroll
        for (int s = 0; s < 2; s++) {
            bf16x8 af[4], bf[4];
#pragma unroll
            for (int ga = 0; ga < 4; ga++)
                af[ga] = *(const bf16x8*)&lA[wo * 4096 + (s * 4 + ga) * 512 + lane * 8];
#pragma unroll
            for (int gb = 0; gb < 4; gb++)
                bf[gb] = *(const bf16x8*)&lB[wm * 4096 + (s * 4 + gb) * 512 + lane * 8];
#pragma unroll
            for (int ga = 0; ga < 4; ga++)
#pragma unroll
                for (int gb = 0; gb < 4; gb++)
                    acc[ga][gb] = __builtin_amdgcn_mfma_f32_16x16x32_bf16(af[ga], bf[gb], acc[ga][gb], 0, 0, 0);
        }
        __syncthreads();
    }

    int quad = lane >> 4, col = lane & 15;
#pragma unroll
    for (int ga = 0; ga < 4; ga++) {
        int ob = o0 + wo * 64 + ga * 16 + quad * 4;
        float bs[4];
#pragma unroll
        for (int r = 0; r < 4; r++) bs[r] = bias[ob + r];
        int Cb2 = ob >> 6, s2 = (ob >> 5) & 1, q8 = (ob >> 3) & 3, j0 = ob & 7;
#pragma unroll
        for (int gb = 0; gb < 4; gb++) {
            int n = m0 + wm * 64 + gb * 16 + col;
            int T = n >> 6, g4 = (n >> 4) & 3, Lm = n & 15;
            union { __bf16 h[4]; float2 f2; } u;
#pragma unroll
            for (int r = 0; r < 4; r++) u.h[r] = (__bf16)(acc[ga][gb][r] + bs[r]);
            *(float2*)&Of[(size_t)(Cb2 * 144 + T) * 4096 + (s2 * 4 + g4) * 512 + (size_t)((q8 << 4) | Lm) * 8 + j0] = u.f2;
        }
    }
}

// ---------------------------------------------------------------------------
// K4: scores GEMM + max. Block tile 192q x 192k, wave tile 96x96 (2x2 waves).
// More FLOP per LDS byte: 288 MFMA (~1400 cyc) vs 144 KB LDS (~1125 cyc).
// ---------------------------------------------------------------------------
__global__ __launch_bounds__(256)
void scores_mfma_kernel(const __bf16* __restrict__ Qf, const __bf16* __restrict__ Kf,
                        float* __restrict__ maxv3)
{
    __shared__ __bf16 ldsQ[12288];   // 3 T-blocks, 24 KB
    __shared__ __bf16 ldsK[12288];   // 3 T-blocks, 24 KB
    __shared__ float redbuf[192][2];

    int tid = threadIdx.x, lane = tid & 63, wv = tid >> 6;
    int wq = wv >> 1, wk = wv & 1;
    int bx = blockIdx.x;             // 0..47 (192-pixel q tile)
    int n0 = bx * 192;
    int b = blockIdx.y / 3, mt = blockIdx.y % 3;

    f32x4 acc[6][6];
#pragma unroll
    for (int ga = 0; ga < 6; ga++)
#pragma unroll
        for (int t = 0; t < 6; t++) acc[ga][t] = (f32x4){0.f, 0.f, 0.f, 0.f};

    const __bf16* qbase = Qf + (size_t)(bx * 3) * 4096;
    const __bf16* kbase = Kf + (size_t)(b * 9 + mt * 3) * 4096;

    for (int C = 0; C < 8; C++) {
        const float4* gq = (const float4*)(qbase + (size_t)C * 144 * 4096);
        const float4* gk = (const float4*)(kbase + (size_t)C * 144 * 4096);
        float4* lq = (float4*)ldsQ;
        float4* lk = (float4*)ldsK;
#pragma unroll
        for (int i = 0; i < 6; i++) {
            lq[tid + i * 256] = gq[tid + i * 256];
            lk[tid + i * 256] = gk[tid + i * 256];
        }
        __syncthreads();
#pragma unroll
        for (int s = 0; s < 2; s++) {
            bf16x8 af[6], bfr[6];
#pragma unroll
            for (int ga = 0; ga < 6; ga++) {
                int qrow = wq * 96 + ga * 16;
                af[ga] = *(const bf16x8*)&ldsQ[(qrow >> 6) * 4096 + (s * 4 + ((qrow >> 4) & 3)) * 512 + lane * 8];
            }
#pragma unroll
            for (int t = 0; t < 6; t++) {
                int krow = wk * 96 + t * 16;
                bfr[t] = *(const bf16x8*)&ldsK[(krow >> 6) * 4096 + (s * 4 + ((krow >> 4) & 3)) * 512 + lane * 8];
            }
#pragma unroll
            for (int ga = 0; ga < 6; ga++)
#pragma unroll
                for (int t = 0; t < 6; t++)
                    acc[ga][t] = __builtin_amdgcn_mfma_f32_16x16x32_bf16(af[ga], bfr[t], acc[ga][t], 0, 0, 0);
        }
        __syncthreads();
    }

    // epilogue: max over k (t regs + 16 col lanes), keep per q row
    float mg[6][4];
#pragma unroll
    for (int ga = 0; ga < 6; ga++)
#pragma unroll
        for (int r = 0; r < 4; r++) {
            float v = acc[ga][0][r];
#pragma unroll
            for (int t = 1; t < 6; t++) v = fmaxf(v, acc[ga][t][r]);
            mg[ga][r] = v;
        }
#pragma unroll
    for (int off = 1; off < 16; off <<= 1)
#pragma unroll
        for (int ga = 0; ga < 6; ga++)
#pragma unroll
            for (int r = 0; r < 4; r++)
                mg[ga][r] = fmaxf(mg[ga][r], __shfl_xor(mg[ga][r], off, 64));

    if ((lane & 15) == 0) {
        int quad = lane >> 4;
#pragma unroll
        for (int ga = 0; ga < 6; ga++)
#pragma unroll
            for (int r = 0; r < 4; r++)
                redbuf[wq * 96 + ga * 16 + quad * 4 + r][wk] = mg[ga][r];
    }
    __syncthreads();
    if (tid < 192) {
        float rv = fmaxf(redbuf[tid][0], redbuf[tid][1]) * SCALE;
        maxv3[((size_t)(n0 + tid) * BB + b) * 3 + mt] = rv;
    }
}

// ---------------------------------------------------------------------------
// K5: approx v, top-4 candidates per image.
// ---------------------------------------------------------------------------
__global__ __launch_bounds__(576)
void topk_kernel(const float* __restrict__ maxv3, int* __restrict__ cand)
{
    __shared__ float sv[576];
    __shared__ float rv_[64];
    __shared__ int ri_[64];
    int bi = blockIdx.x, m = threadIdx.x;
    int n = bi * HWW + m;
    float v = 0.f;
#pragma unroll
    for (int t = 0; t < BB; t++) {
        const float* p = maxv3 + ((size_t)n * BB + t) * 3;
        v += fmaxf(fmaxf(p[0], p[1]), p[2]);
    }
    sv[m] = v;
    __syncthreads();
    for (int r = 0; r < 4; r++) {
        if (m < 64) {
            float bv = sv[m]; int bidx = m;
            for (int j = m + 64; j < 576; j += 64)
                if (sv[j] > bv) { bv = sv[j]; bidx = j; }
            rv_[m] = bv; ri_[m] = bidx;
        }
        __syncthreads();
        if (m == 0) {
            float bv = rv_[0]; int bidx = ri_[0];
            for (int j = 1; j < 64; j++)
                if (rv_[j] > bv) { bv = rv_[j]; bidx = ri_[j]; }
            cand[bi * 4 + r] = bidx;
            sv[bidx] = -3.4e38f;
        }
        __syncthreads();
    }
}

// ---------------------------------------------------------------------------
// K6a: q = Qw * xcol + qb for each candidate. grid (8 row-groups, 64 cands).
// Coalesced: one row per wave pass, lanes over c.
// ---------------------------------------------------------------------------
__global__ __launch_bounds__(256)
void refine_q_kernel(const float* __restrict__ x5, const float* __restrict__ qw,
                     const float* __restrict__ qb, const int* __restrict__ cand,
                     float* __restrict__ q_all)
{
    int og = blockIdx.x, cd = blockIdx.y;
    int bi = cd >> 2;
    int mstar = cand[cd];
    int tid = threadIdx.x, w = tid >> 6, lane = tid & 63;
    __shared__ float xcol[512];
    __shared__ float qrows[64];
    xcol[tid]       = x5[(size_t)bi * CHW + tid * HWW + mstar];
    xcol[tid + 256] = x5[(size_t)bi * CHW + (tid + 256) * HWW + mstar];
    __syncthreads();
#pragma unroll
    for (int i = 0; i < 16; i++) {
        int r = og * 64 + w * 16 + i;
        float p = 0.f;
#pragma unroll
        for (int it = 0; it < 8; it++) {
            int c = lane + it * 64;
            p = fmaf(qw[(size_t)r * 512 + c], xcol[c], p);
        }
        for (int off = 32; off; off >>= 1) p += __shfl_down(p, off, 64);
        if (lane == 0) qrows[w * 16 + i] = p;
    }
    __syncthreads();
    if (tid < 64) q_all[(size_t)cd * 512 + og * 64 + tid] = qrows[tid] + qb[og * 64 + tid];
}

// ---------------------------------------------------------------------------
// K6b: u[t] = sum_o Kw[o,t]*q[o] (coalesced kw), + qkb. grid (2 t-halves, 64).
// ---------------------------------------------------------------------------
__global__ __launch_bounds__(256)
void refine_u2_kernel(const float* __restrict__ kw, const float* __restrict__ kb,
                      const float* __restrict__ q_all, float* __restrict__ u_all,
                      float* __restrict__ qkbg)
{
    int tg = blockIdx.x, cd = blockIdx.y;
    int tid = threadIdx.x;
    __shared__ float qs[512];
    qs[tid]       = q_all[(size_t)cd * 512 + tid];
    qs[tid + 256] = q_all[(size_t)cd * 512 + tid + 256];
    __syncthreads();
    int t = tg * 256 + tid;
    float u = 0.f;
    for (int o = 0; o < 512; o++)
        u = fmaf(kw[(size_t)o * 512 + t], qs[o], u);
    u_all[(size_t)cd * 512 + t] = u;
    if (tg == 0) {
        float pk = qs[tid] * kb[tid] + qs[tid + 256] * kb[tid + 256];
        for (int off = 32; off; off >>= 1) pk += __shfl_down(pk, off, 64);
        __shared__ float pr[4];
        if ((tid & 63) == 0) pr[tid >> 6] = pk;
        __syncthreads();
        if (tid == 0) qkbg[cd] = pr[0] + pr[1] + pr[2] + pr[3];
    }
}

// ---------------------------------------------------------------------------
// K7: maxex9[cd][bp][mc] = max over 64-pixel chunk of u.x5[bp,:,m].
// grid (16 bp, 4 cand-groups, 9 m-chunks) = 576 blocks.
// threads = 64 pixels x 4 c-slices (one slice per wave -> LDS broadcast).
// ---------------------------------------------------------------------------
__global__ __launch_bounds__(256)
void refine_max_kernel(const float* __restrict__ x5, const float* __restrict__ u_all,
                       float* __restrict__ maxex9)
{
    int bp = blockIdx.x, cg = blockIdx.y, mc = blockIdx.z;
    int tid = threadIdx.x, mi = tid & 63, cs = tid >> 6;
    int m0 = mc * 64;
    __shared__ float us[16 * 512];   // 32 KB
    __shared__ float red[256];
    for (int e = tid; e < 16 * 512; e += 256) us[e] = u_all[(size_t)cg * 16 * 512 + e];
    __syncthreads();

    float acc[16];
#pragma unroll
    for (int j = 0; j < 16; j++) acc[j] = 0.f;
    const float* xb = x5 + (size_t)bp * CHW + m0 + mi;
    for (int cc = 0; cc < 128; cc++) {
        int c = cs * 128 + cc;
        float x = xb[(size_t)c * HWW];
#pragma unroll
        for (int j = 0; j < 16; j++)
            acc[j] = fmaf(us[j * 512 + c], x, acc[j]);
    }

#pragma unroll
    for (int j = 0; j < 16; j++) {
        red[tid] = acc[j];
        __syncthreads();
        if (tid < 64) {
            float v = red[tid] + red[tid + 64] + red[tid + 128] + red[tid + 192];
            for (int off = 32; off; off >>= 1) v = fmaxf(v, __shfl_xor(v, off, 64));
            if (tid == 0) maxex9[((size_t)(cg * 16 + j) * BB + bp) * 9 + mc] = v;
        }
        __syncthreads();
    }
}

// ---------------------------------------------------------------------------
// K8: exact argmax among candidates -> one-hot mask
// ---------------------------------------------------------------------------
__global__ __launch_bounds__(576)
void mask_kernel(const float* __restrict__ maxex9, const float* __restrict__ qkbg,
                 const int* __restrict__ cand, float* __restrict__ maskout)
{
    int bi = blockIdx.x, m = threadIdx.x;
    __shared__ float ve[4];
    __shared__ int chosen;
    if (m < 4) {
        int cd = bi * 4 + m;
        float sacc = 0.f;
#pragma unroll
        for (int t = 0; t < BB; t++) {
            const float* p = maxex9 + ((size_t)cd * BB + t) * 9;
            float mv = p[0];
#pragma unroll
            for (int z = 1; z < 9; z++) mv = fmaxf(mv, p[z]);
            sacc += mv;
        }
        ve[m] = sacc * (1.f / 16.f) + qkbg[cd];
    }
    __syncthreads();
    if (m == 0) {
        int best = 0; float bv = ve[0];
        for (int j = 1; j < 4; j++) if (ve[j] > bv) { bv = ve[j]; best = j; }
        chosen = cand[bi * 4 + best];
    }
    __syncthreads();
    maskout[bi * HWW + m] = (m == chosen) ? 1.f : 0.f;
}

// ---------------------------------------------------------------------------
// K9..K14: fp32 tail (unchanged)
// ---------------------------------------------------------------------------
__global__ __launch_bounds__(256)
void norm_kernel(const float* __restrict__ X5, float* __restrict__ invb)
{
    int b = blockIdx.y;
    int m0 = blockIdx.x * 64;
    int mi = threadIdx.x & 63, cs = threadIdx.x >> 6;
    float s = 0.f;
    for (int c = cs; c < CC; c += 4) {
        float x = X5[b * CHW + c * HWW + m0 + mi];
        s = fmaf(x, x, s);
    }
    __shared__ float red[4][64];
    red[cs][mi] = s;
    __syncthreads();
    if (cs == 0) {
        float t = red[0][mi] + red[1][mi] + red[2][mi] + red[3][mi];
        invb[b * HWW + m0 + mi] = 1.0f / fmaxf(sqrtf(t), 1e-12f);
    }
}

__global__ __launch_bounds__(256)
void seeds_kernel(const float* __restrict__ X5, const float* __restrict__ invb,
                  const float* __restrict__ maskf, float* __restrict__ seeds)
{
    int s = blockIdx.y;
    int c = blockIdx.x * 4 + (threadIdx.x >> 6);
    int mi = threadIdx.x & 63;
    float acc = 0.f;
    for (int mt = 0; mt < 9; mt++) {
        int m = mt * 64 + mi;
        float w = invb[s * HWW + m] * maskf[s * HWW + m];
        acc = fmaf(X5[s * CHW + c * HWW + m], w, acc);
    }
    for (int off = 32; off > 0; off >>= 1) acc += __shfl_down(acc, off, 64);
    if (mi == 0) seeds[s * CC + c] = acc;
}

__global__ __launch_bounds__(256)
void corr_kernel(const float* __restrict__ X5, const float* __restrict__ invb,
                 const float* __restrict__ seeds, float* __restrict__ corr)
{
    __shared__ float sd[16 * 512];
    __shared__ float xs[64][65];
    __shared__ float red[4][64];
    int b = blockIdx.y;
    int m0 = blockIdx.x * 64;
    int tid = threadIdx.x;
    int mi = tid & 63, sg = tid >> 6;

    for (int e = tid; e < 16 * 512; e += 256) sd[e] = seeds[e];

    float acc[4] = {0.f, 0.f, 0.f, 0.f};
    for (int c0 = 0; c0 < CC; c0 += 64) {
        __syncthreads();
        for (int e = tid; e < 4096; e += 256) {
            int mm = e & 63, kk = e >> 6;
            xs[kk][mm] = X5[b * CHW + (c0 + kk) * HWW + m0 + mm];
        }
        __syncthreads();
#pragma unroll
        for (int kk = 0; kk < 64; kk++) {
            float xv = xs[kk][mi];
#pragma unroll
            for (int t = 0; t < 4; t++)
                acc[t] = fmaf(xv, sd[(sg * 4 + t) * CC + c0 + kk], acc[t]);
        }
    }
    float r = 0.f;
#pragma unroll
    for (int t = 0; t < 4; t++) r += fmaxf(acc[t], 0.f);
    red[sg][mi] = r;
    __syncthreads();
    if (sg == 0) {
        float tot = red[0][mi] + red[1][mi] + red[2][mi] + red[3][mi];
        corr[b * HWW + m0 + mi] = invb[b * HWW + m0 + mi] * tot * (1.0f / 16.0f);
    }
}

__global__ __launch_bounds__(576)
void cormap_kernel(const float* __restrict__ corr, float* __restrict__ cormap)
{
    __shared__ float sv[576];
    __shared__ float smn[64], smx[64];
    __shared__ float s_mn, s_mx;
    int b = blockIdx.x;
    int m = threadIdx.x;
    float v = corr[b * HWW + m];
    sv[m] = v;
    __syncthreads();
    if (m < 64) {
        float mn = sv[m], mx = sv[m];
        for (int j = m + 64; j < 576; j += 64) { mn = fminf(mn, sv[j]); mx = fmaxf(mx, sv[j]); }
        smn[m] = mn; smx[m] = mx;
    }
    __syncthreads();
    if (m == 0) {
        float mn = smn[0], mx = smx[0];
        for (int j = 1; j < 64; j++) { mn = fminf(mn, smn[j]); mx = fmaxf(mx, smx[j]); }
        s_mn = mn; s_mx = mx;
    }
    __syncthreads();
    cormap[b * HWW + m] = (v - s_mn) / (s_mx - s_mn + 1e-12f);
}

__global__ __launch_bounds__(256)
void proto_kernel(const float* __restrict__ X5, const float* __restrict__ cormap,
                  float* __restrict__ proto1)
{
    int c = blockIdx.x;
    int tid = threadIdx.x;
    float acc = 0.f;
    for (int p = tid; p < NN; p += 256) {
        int b = p / HWW, m = p % HWW;
        acc = fmaf(X5[b * CHW + c * HWW + m], cormap[p], acc);
    }
    for (int off = 32; off > 0; off >>= 1) acc += __shfl_down(acc, off, 64);
    __shared__ float red[4];
    if ((tid & 63) == 0) red[tid >> 6] = acc;
    __syncthreads();
    if (tid == 0) proto1[c] = (red[0] + red[1] + red[2] + red[3]) * (1.0f / (float)NN);
}

__global__ __launch_bounds__(256)
void final_kernel(const float* __restrict__ X5, const float* __restrict__ proto1,
                  const float* __restrict__ cormap, float* __restrict__ out3)
{
    int idx = blockIdx.x * 256 + threadIdx.x;
    if (idx >= TOT) return;
    int b = idx / CHW;
    int r = idx % CHW;
    int c = r / HWW;
    int m = r % HWW;
    float x = X5[idx];
    out3[idx] = x * (proto1[c] + cormap[b * HWW + m]);
}

// ---------------------------------------------------------------------------
extern "C" void kernel_launch(void* const* d_in, const int* in_sizes, int n_in,
                              void* d_out, int out_size, void* d_ws, size_t ws_size,
                              hipStream_t stream)
{
    const float* x  = (const float*)d_in[0];
    const float* cw = (const float*)d_in[1];
    const float* cb = (const float*)d_in[2];
    const float* qw = (const float*)d_in[3];
    const float* qb = (const float*)d_in[4];
    const float* kw = (const float*)d_in[5];
    const float* kb = (const float*)d_in[6];

    float* out     = (float*)d_out;
    float* x5o     = out;                        // output 0
    float* proto1  = out + TOT;                  // output 1
    float* out3    = out + TOT + 512;            // output 2
    float* maskout = out + TOT + 512 + TOT;      // output 3

    // out3 region overlays (all consumed before final_kernel writes out3):
    char* o3 = (char*)out3;
    __bf16* xlo    = (__bf16*)o3;
    __bf16* qfrag  = (__bf16*)o3;                // overwrites xlo after conv1
    __bf16* x5frag = (__bf16*)(o3 + FRAGB);

    // ws layout:
    char* ws = (char*)d_ws;
    __bf16* xhi   = (__bf16*)ws;                 // -> later kfrag (same slot)
    __bf16* kfrag = (__bf16*)ws;
    __bf16* cwhi  = (__bf16*)(ws + FRAGB);
    __bf16* cwlo  = (__bf16*)(ws + FRAGB + 524288);
    __bf16* qwf   = (__bf16*)(ws + FRAGB + 2 * 524288);
    __bf16* kwf   = (__bf16*)(ws + FRAGB + 3 * 524288);
    char* p = ws + FRAGB + 4 * 524288;
    float* maxv3  = (float*)p;   p += (size_t)NN * BB * 3 * 4;
    int*   cand   = (int*)p;     p += 256;
    float* q_all  = (float*)p;   p += 64 * 512 * 4;
    float* u_all  = (float*)p;   p += 64 * 512 * 4;
    float* qkbg   = (float*)p;   p += 256;
    float* maxex9 = (float*)p;   p += 64 * BB * 9 * 4;
    float* invb   = (float*)p;   p += NN * 4;
    float* corr   = (float*)p;   p += NN * 4;
    float* cmap   = (float*)p;   p += NN * 4;
    float* seeds  = (float*)p;   p += BB * CC * 4;

    prep_x_kernel<<<NN * 64 / 256, 256, 0, stream>>>(x, xhi, xlo);
    prep_w_kernel<<<dim3(128, 3), 256, 0, stream>>>(cw, qw, kw, cwhi, cwlo, qwf, kwf);

    conv1_mfma_kernel<<<dim3(NN / 128, 4), 256, 0, stream>>>(x, cwhi, cwlo, xhi, xlo, cb, x5o, x5frag);
    convqk_mfma_kernel<<<dim3(NN / 128, 4, 2), 256, 0, stream>>>(qwf, kwf, qb, kb, x5frag, qfrag, kfrag);

    scores_mfma_kernel<<<dim3(NN / 192, BB * 3), 256, 0, stream>>>(qfrag, kfrag, maxv3);

    topk_kernel<<<BB, HWW, 0, stream>>>(maxv3, cand);
    refine_q_kernel<<<dim3(8, 64), 256, 0, stream>>>(x5o, qw, qb, cand, q_all);
    refine_u2_kernel<<<dim3(2, 64), 256, 0, stream>>>(kw, kb, q_all, u_all, qkbg);
    refine_max_kernel<<<dim3(BB, 4, 9), 256, 0, stream>>>(x5o, u_all, maxex9);
    mask_kernel<<<BB, HWW, 0, stream>>>(maxex9, qkbg, cand, maskout);

    norm_kernel<<<dim3(9, BB), 256, 0, stream>>>(x5o, invb);
    seeds_kernel<<<dim3(CC / 4, BB), 256, 0, stream>>>(x5o, invb, maskout, seeds);
    corr_kernel<<<dim3(9, BB), 256, 0, stream>>>(x5o, invb, seeds, corr);
    cormap_kernel<<<BB, HWW, 0, stream>>>(corr, cmap);
    proto_kernel<<<CC, 256, 0, stream>>>(x5o, cmap, proto1);
    final_kernel<<<(TOT + 255) / 256, 256, 0, stream>>>(x5o, proto1, cmap, out3);
}

// Round 5
// 376.561 us; speedup vs baseline: 7.2379x; 1.1165x over previous
//
#include <hip/hip_runtime.h>
#include <math.h>

#define BB   16
#define CC   512
#define HWW  576
#define NN   9216            // B*HW
#define CHW  (CC*HWW)        // 294912
#define TOT  (BB*CHW)        // 4718592
#define SCALE 0.044194173824159216f  // 1/sqrt(512)
#define FRAGB 9437184        // NN*CC bf16 bytes

typedef __attribute__((ext_vector_type(8))) __bf16 bf16x8;
typedef __attribute__((ext_vector_type(4))) float f32x4;

#define AS1 __attribute__((address_space(1)))
#define AS3 __attribute__((address_space(3)))

// async 16B global->LDS: lds dest = wave-uniform base + lane*16
static __device__ __forceinline__ void gload_lds16(const void* g, void* l)
{
    __builtin_amdgcn_global_load_lds((AS1 const void*)g, (AS3 void*)l, 16, 0, 0);
}

// ---------------------------------------------------------------------------
// Fragment-linear bf16 layout (MFMA A/B operand order), 64x64 (dim,k) blocks:
//   slot(elem) = (s*4+g4)*512 + L*8 + j,  L = (q8<<4)|Lm
//   dim64 = g4*16 + Lm,   k64 = s*32 + q8*8 + j
// X/x5/q/k ("B-side", dim=pixel, k=channel): block index [Cb*144 + T]
// W ("A-side", dim=out-chan, k=in-chan):     block index [Cb*8  + To]
// Frag read for mfma_16x16x32_bf16: contiguous 16 B at lane*16.
// ---------------------------------------------------------------------------

// P1: x -> hi/lo bf16 fragment layout
__global__ __launch_bounds__(256)
void prep_x_kernel(const float* __restrict__ X, __bf16* __restrict__ Xhi,
                   __bf16* __restrict__ Xlo)
{
    int g = blockIdx.x * 256 + threadIdx.x;   // NN*64 threads
    int n = g % NN;
    int co = g / NN;                          // channel octet 0..63
    int c0 = co * 8;
    int bimg = n / HWW, mm = n % HWW;
    const float* src = X + (size_t)bimg * CHW + mm;
    union { __bf16 h[8]; float4 f4; } uh, ul;
#pragma unroll
    for (int j = 0; j < 8; j++) {
        float v = src[(size_t)(c0 + j) * HWW];
        __bf16 h = (__bf16)v;
        uh.h[j] = h;
        ul.h[j] = (__bf16)(v - (float)h);
    }
    int Cb = c0 >> 6, s = (c0 >> 5) & 1, q8 = (c0 >> 3) & 3;
    int T = n >> 6, g4 = (n >> 4) & 3, Lm = n & 15;
    size_t off = (size_t)(Cb * 144 + T) * 4096 + (s * 4 + g4) * 512 + (size_t)((q8 << 4) | Lm) * 8;
    *(float4*)&Xhi[off] = uh.f4;
    *(float4*)&Xlo[off] = ul.f4;
}

// P2: weights -> fragment layout. y=0: cw (hi+lo), y=1: qw, y=2: kw
__global__ __launch_bounds__(256)
void prep_w_kernel(const float* __restrict__ cw, const float* __restrict__ qw,
                   const float* __restrict__ kw, __bf16* __restrict__ cwhi,
                   __bf16* __restrict__ cwlo, __bf16* __restrict__ qwf,
                   __bf16* __restrict__ kwf)
{
    int y = blockIdx.y;
    const float* W = (y == 0) ? cw : (y == 1) ? qw : kw;
    __bf16* dh = (y == 0) ? cwhi : (y == 1) ? qwf : kwf;
    int g = blockIdx.x * 256 + threadIdx.x;   // 512*64 threads
    int o = g >> 6;
    int c0 = (g & 63) * 8;
    union { __bf16 h[8]; float4 f4; } uh, ul;
#pragma unroll
    for (int j = 0; j < 8; j++) {
        float v = W[(size_t)o * CC + c0 + j];
        __bf16 h = (__bf16)v;
        uh.h[j] = h;
        ul.h[j] = (__bf16)(v - (float)h);
    }
    int Cb = c0 >> 6, s = (c0 >> 5) & 1, q8 = (c0 >> 3) & 3;
    int To = o >> 6, g4 = (o >> 4) & 3, Lm = o & 15;
    size_t off = (size_t)(Cb * 8 + To) * 4096 + (s * 4 + g4) * 512 + (size_t)((q8 << 4) | Lm) * 8;
    *(float4*)&dh[off] = uh.f4;
    if (y == 0) *(float4*)&cwlo[off] = ul.f4;
}

// ---------------------------------------------------------------------------
// K1: x5 conv via hi/lo bf16 MFMA (fp32-class accuracy) + residual + bias.
// ---------------------------------------------------------------------------
__global__ __launch_bounds__(256)
void conv1_mfma_kernel(const float* __restrict__ X, const __bf16* __restrict__ Whi,
                       const __bf16* __restrict__ Wlo, const __bf16* __restrict__ Xhi,
                       const __bf16* __restrict__ Xlo, const float* __restrict__ bias,
                       float* __restrict__ Y, __bf16* __restrict__ Yfrag)
{
    __shared__ __bf16 lAh[8192], lAl[8192], lBh[8192], lBl[8192];
    int tid = threadIdx.x, lane = tid & 63, wv = tid >> 6;
    int wo = wv >> 1, wm = wv & 1;
    int m0 = blockIdx.x * 128;
    int o0 = blockIdx.y * 128;
    int oT0 = blockIdx.y * 2, mT0 = blockIdx.x * 2;

    f32x4 acc[4][4];
#pragma unroll
    for (int i = 0; i < 4; i++)
#pragma unroll
        for (int j = 0; j < 4; j++) acc[i][j] = (f32x4){0.f, 0.f, 0.f, 0.f};

    for (int Cb = 0; Cb < 8; Cb++) {
        const float4* gAh = (const float4*)(Whi + (size_t)(Cb * 8 + oT0) * 4096);
        const float4* gAl = (const float4*)(Wlo + (size_t)(Cb * 8 + oT0) * 4096);
        const float4* gBh = (const float4*)(Xhi + (size_t)(Cb * 144 + mT0) * 4096);
        const float4* gBl = (const float4*)(Xlo + (size_t)(Cb * 144 + mT0) * 4096);
#pragma unroll
        for (int i = 0; i < 4; i++) {
            int eb = wv * 256 + i * 64;
            gload_lds16(gAh + eb + lane, (float4*)lAh + eb);
            gload_lds16(gAl + eb + lane, (float4*)lAl + eb);
            gload_lds16(gBh + eb + lane, (float4*)lBh + eb);
            gload_lds16(gBl + eb + lane, (float4*)lBl + eb);
        }
        __syncthreads();
#pragma unroll
        for (int s = 0; s < 2; s++) {
            bf16x8 ah[4], al[4], bh[4], bl[4];
#pragma unroll
            for (int ga = 0; ga < 4; ga++) {
                ah[ga] = *(const bf16x8*)&lAh[wo * 4096 + (s * 4 + ga) * 512 + lane * 8];
                al[ga] = *(const bf16x8*)&lAl[wo * 4096 + (s * 4 + ga) * 512 + lane * 8];
            }
#pragma unroll
            for (int gb = 0; gb < 4; gb++) {
                bh[gb] = *(const bf16x8*)&lBh[wm * 4096 + (s * 4 + gb) * 512 + lane * 8];
                bl[gb] = *(const bf16x8*)&lBl[wm * 4096 + (s * 4 + gb) * 512 + lane * 8];
            }
#pragma unroll
            for (int ga = 0; ga < 4; ga++)
#pragma unroll
                for (int gb = 0; gb < 4; gb++) {
                    acc[ga][gb] = __builtin_amdgcn_mfma_f32_16x16x32_bf16(ah[ga], bh[gb], acc[ga][gb], 0, 0, 0);
                    acc[ga][gb] = __builtin_amdgcn_mfma_f32_16x16x32_bf16(ah[ga], bl[gb], acc[ga][gb], 0, 0, 0);
                    acc[ga][gb] = __builtin_amdgcn_mfma_f32_16x16x32_bf16(al[ga], bh[gb], acc[ga][gb], 0, 0, 0);
                }
        }
        __syncthreads();
    }

    int quad = lane >> 4, col = lane & 15;
#pragma unroll
    for (int ga = 0; ga < 4; ga++) {
        int ob = o0 + wo * 64 + ga * 16 + quad * 4;
        float bs[4];
#pragma unroll
        for (int r = 0; r < 4; r++) bs[r] = bias[ob + r];
        int Cb2 = ob >> 6, s2 = (ob >> 5) & 1, q8 = (ob >> 3) & 3, j0 = ob & 7;
#pragma unroll
        for (int gb = 0; gb < 4; gb++) {
            int n = m0 + wm * 64 + gb * 16 + col;
            int T = n >> 6, g4 = (n >> 4) & 3, Lm = n & 15;
            int bimg = n / HWW, mm = n % HWW;
            size_t xb = (size_t)bimg * CHW + mm;
            union { __bf16 h[4]; float2 f2; } u;
#pragma unroll
            for (int r = 0; r < 4; r++) {
                float v = acc[ga][gb][r] + bs[r] + X[xb + (size_t)(ob + r) * HWW];
                Y[xb + (size_t)(ob + r) * HWW] = v;
                u.h[r] = (__bf16)v;
            }
            *(float2*)&Yfrag[(size_t)(Cb2 * 144 + T) * 4096 + (s2 * 4 + g4) * 512 + (size_t)((q8 << 4) | Lm) * 8 + j0] = u.f2;
        }
    }
}

// ---------------------------------------------------------------------------
// K2: q & k convs via plain bf16 MFMA from x5 fragment layout.
// ---------------------------------------------------------------------------
__global__ __launch_bounds__(256)
void convqk_mfma_kernel(const __bf16* __restrict__ qwf, const __bf16* __restrict__ kwf,
                        const float* __restrict__ qb, const float* __restrict__ kb,
                        const __bf16* __restrict__ Xf, __bf16* __restrict__ Oq,
                        __bf16* __restrict__ Ok)
{
    const __bf16* Wf = blockIdx.z ? kwf : qwf;
    const float* bias = blockIdx.z ? kb : qb;
    __bf16* Of = blockIdx.z ? Ok : Oq;

    __shared__ __bf16 lA[8192], lB[8192];
    int tid = threadIdx.x, lane = tid & 63, wv = tid >> 6;
    int wo = wv >> 1, wm = wv & 1;
    int m0 = blockIdx.x * 128;
    int o0 = blockIdx.y * 128;
    int oT0 = blockIdx.y * 2, mT0 = blockIdx.x * 2;

    f32x4 acc[4][4];
#pragma unroll
    for (int i = 0; i < 4; i++)
#pragma unroll
        for (int j = 0; j < 4; j++) acc[i][j] = (f32x4){0.f, 0.f, 0.f, 0.f};

    for (int Cb = 0; Cb < 8; Cb++) {
        const float4* gA = (const float4*)(Wf + (size_t)(Cb * 8 + oT0) * 4096);
        const float4* gB = (const float4*)(Xf + (size_t)(Cb * 144 + mT0) * 4096);
#pragma unroll
        for (int i = 0; i < 4; i++) {
            int eb = wv * 256 + i * 64;
            gload_lds16(gA + eb + lane, (float4*)lA + eb);
            gload_lds16(gB + eb + lane, (float4*)lB + eb);
        }
        __syncthreads();
#pragma unroll
        for (int s = 0; s < 2; s++) {
            bf16x8 af[4], bf[4];
#pragma unroll
            for (int ga = 0; ga < 4; ga++)
                af[ga] = *(const bf16x8*)&lA[wo * 4096 + (s * 4 + ga) * 512 + lane * 8];
#pragma unroll
            for (int gb = 0; gb < 4; gb++)
                bf[gb] = *(const bf16x8*)&lB[wm * 4096 + (s * 4 + gb) * 512 + lane * 8];
#pragma unroll
            for (int ga = 0; ga < 4; ga++)
#pragma unroll
                for (int gb = 0; gb < 4; gb++)
                    acc[ga][gb] = __builtin_amdgcn_mfma_f32_16x16x32_bf16(af[ga], bf[gb], acc[ga][gb], 0, 0, 0);
        }
        __syncthreads();
    }

    int quad = lane >> 4, col = lane & 15;
#pragma unroll
    for (int ga = 0; ga < 4; ga++) {
        int ob = o0 + wo * 64 + ga * 16 + quad * 4;
        float bs[4];
#pragma unroll
        for (int r = 0; r < 4; r++) bs[r] = bias[ob + r];
        int Cb2 = ob >> 6, s2 = (ob >> 5) & 1, q8 = (ob >> 3) & 3, j0 = ob & 7;
#pragma unroll
        for (int gb = 0; gb < 4; gb++) {
            int n = m0 + wm * 64 + gb * 16 + col;
            int T = n >> 6, g4 = (n >> 4) & 3, Lm = n & 15;
            union { __bf16 h[4]; float2 f2; } u;
#pragma unroll
            for (int r = 0; r < 4; r++) u.h[r] = (__bf16)(acc[ga][gb][r] + bs[r]);
            *(float2*)&Of[(size_t)(Cb2 * 144 + T) * 4096 + (s2 * 4 + g4) * 512 + (size_t)((q8 << 4) | Lm) * 8 + j0] = u.f2;
        }
    }
}

// ---------------------------------------------------------------------------
// K4: scores GEMM + max. Block 128q x 192k, wave tile 64x96 (round-3 shape),
// async global_load_lds staging, LDS exactly 40 KB -> 4 blocks/CU.
// ---------------------------------------------------------------------------
__global__ __launch_bounds__(256)
void scores_mfma_kernel(const __bf16* __restrict__ Qf, const __bf16* __restrict__ Kf,
                        float* __restrict__ maxv3)
{
    __shared__ __bf16 ldsQ[8192];    // 16 KB: 2 T-blocks (redbuf aliases this)
    __shared__ __bf16 ldsK[12288];   // 24 KB: 3 T-blocks

    int tid = threadIdx.x, lane = tid & 63, wv = tid >> 6;
    int wq = wv >> 1, wk = wv & 1;
    int bx = blockIdx.x;
    int n0 = bx * 128;
    int b = blockIdx.y / 3, mt = blockIdx.y % 3;

    f32x4 acc[4][6];
#pragma unroll
    for (int ga = 0; ga < 4; ga++)
#pragma unroll
        for (int t = 0; t < 6; t++) acc[ga][t] = (f32x4){0.f, 0.f, 0.f, 0.f};

    const __bf16* qbase = Qf + (size_t)(bx * 2) * 4096;
    const __bf16* kbase = Kf + (size_t)(b * 9 + mt * 3) * 4096;

    for (int C = 0; C < 8; C++) {
        const float4* gq = (const float4*)(qbase + (size_t)C * 144 * 4096);
        const float4* gk = (const float4*)(kbase + (size_t)C * 144 * 4096);
#pragma unroll
        for (int i = 0; i < 4; i++) {
            int eb = wv * 256 + i * 64;
            gload_lds16(gq + eb + lane, (float4*)ldsQ + eb);
        }
#pragma unroll
        for (int i = 0; i < 6; i++) {
            int eb = wv * 384 + i * 64;
            gload_lds16(gk + eb + lane, (float4*)ldsK + eb);
        }
        __syncthreads();
#pragma unroll
        for (int s = 0; s < 2; s++) {
            bf16x8 af[4];
#pragma unroll
            for (int ga = 0; ga < 4; ga++)
                af[ga] = *(const bf16x8*)&ldsQ[wq * 4096 + (s * 4 + ga) * 512 + lane * 8];
#pragma unroll
            for (int t = 0; t < 6; t++) {
                int mkl = wk * 96 + t * 16;
                bf16x8 bfr = *(const bf16x8*)&ldsK[(mkl >> 6) * 4096 + (s * 4 + ((mkl >> 4) & 3)) * 512 + lane * 8];
#pragma unroll
                for (int ga = 0; ga < 4; ga++)
                    acc[ga][t] = __builtin_amdgcn_mfma_f32_16x16x32_bf16(af[ga], bfr, acc[ga][t], 0, 0, 0);
            }
        }
        __syncthreads();
    }

    // epilogue: max over mk (t regs + 16 col lanes), keep per mq row
    float mg[4][4];
#pragma unroll
    for (int ga = 0; ga < 4; ga++)
#pragma unroll
        for (int r = 0; r < 4; r++) {
            float v = acc[ga][0][r];
#pragma unroll
            for (int t = 1; t < 6; t++) v = fmaxf(v, acc[ga][t][r]);
            mg[ga][r] = v;
        }
#pragma unroll
    for (int off = 1; off < 16; off <<= 1)
#pragma unroll
        for (int ga = 0; ga < 4; ga++)
#pragma unroll
            for (int r = 0; r < 4; r++)
                mg[ga][r] = fmaxf(mg[ga][r], __shfl_xor(mg[ga][r], off, 64));

    float (*redbuf)[2] = (float (*)[2])ldsQ;   // alias (post-loop, after barrier)
    if ((lane & 15) == 0) {
        int quad = lane >> 4;
#pragma unroll
        for (int ga = 0; ga < 4; ga++)
#pragma unroll
            for (int r = 0; r < 4; r++)
                redbuf[wq * 64 + ga * 16 + quad * 4 + r][wk] = mg[ga][r];
    }
    __syncthreads();
    if (tid < 128) {
        float rv = fmaxf(redbuf[tid][0], redbuf[tid][1]) * SCALE;
        maxv3[((size_t)(n0 + tid) * BB + b) * 3 + mt] = rv;
    }
}

// ---------------------------------------------------------------------------
// K5: approx v, top-4 candidates per image.
// ---------------------------------------------------------------------------
__global__ __launch_bounds__(576)
void topk_kernel(const float* __restrict__ maxv3, int* __restrict__ cand)
{
    __shared__ float sv[576];
    __shared__ float rv_[64];
    __shared__ int ri_[64];
    int bi = blockIdx.x, m = threadIdx.x;
    int n = bi * HWW + m;
    float v = 0.f;
#pragma unroll
    for (int t = 0; t < BB; t++) {
        const float* p = maxv3 + ((size_t)n * BB + t) * 3;
        v += fmaxf(fmaxf(p[0], p[1]), p[2]);
    }
    sv[m] = v;
    __syncthreads();
    for (int r = 0; r < 4; r++) {
        if (m < 64) {
            float bv = sv[m]; int bidx = m;
            for (int j = m + 64; j < 576; j += 64)
                if (sv[j] > bv) { bv = sv[j]; bidx = j; }
            rv_[m] = bv; ri_[m] = bidx;
        }
        __syncthreads();
        if (m == 0) {
            float bv = rv_[0]; int bidx = ri_[0];
            for (int j = 1; j < 64; j++)
                if (rv_[j] > bv) { bv = rv_[j]; bidx = ri_[j]; }
            cand[bi * 4 + r] = bidx;
            sv[bidx] = -3.4e38f;
        }
        __syncthreads();
    }
}

// ---------------------------------------------------------------------------
// K6a: q = Qw * xcol + qb for each candidate.
// ---------------------------------------------------------------------------
__global__ __launch_bounds__(256)
void refine_q_kernel(const float* __restrict__ x5, const float* __restrict__ qw,
                     const float* __restrict__ qb, const int* __restrict__ cand,
                     float* __restrict__ q_all)
{
    int og = blockIdx.x, cd = blockIdx.y;
    int bi = cd >> 2;
    int mstar = cand[cd];
    int tid = threadIdx.x, w = tid >> 6, lane = tid & 63;
    __shared__ float xcol[512];
    __shared__ float qrows[64];
    xcol[tid]       = x5[(size_t)bi * CHW + tid * HWW + mstar];
    xcol[tid + 256] = x5[(size_t)bi * CHW + (tid + 256) * HWW + mstar];
    __syncthreads();
#pragma unroll
    for (int i = 0; i < 16; i++) {
        int r = og * 64 + w * 16 + i;
        float p = 0.f;
#pragma unroll
        for (int it = 0; it < 8; it++) {
            int c = lane + it * 64;
            p = fmaf(qw[(size_t)r * 512 + c], xcol[c], p);
        }
        for (int off = 32; off; off >>= 1) p += __shfl_down(p, off, 64);
        if (lane == 0) qrows[w * 16 + i] = p;
    }
    __syncthreads();
    if (tid < 64) q_all[(size_t)cd * 512 + og * 64 + tid] = qrows[tid] + qb[og * 64 + tid];
}

// ---------------------------------------------------------------------------
// K6b: u[t] = sum_o Kw[o,t]*q[o] (coalesced kw), + qkb.
// ---------------------------------------------------------------------------
__global__ __launch_bounds__(256)
void refine_u2_kernel(const float* __restrict__ kw, const float* __restrict__ kb,
                      const float* __restrict__ q_all, float* __restrict__ u_all,
                      float* __restrict__ qkbg)
{
    int tg = blockIdx.x, cd = blockIdx.y;
    int tid = threadIdx.x;
    __shared__ float qs[512];
    qs[tid]       = q_all[(size_t)cd * 512 + tid];
    qs[tid + 256] = q_all[(size_t)cd * 512 + tid + 256];
    __syncthreads();
    int t = tg * 256 + tid;
    float u = 0.f;
    for (int o = 0; o < 512; o++)
        u = fmaf(kw[(size_t)o * 512 + t], qs[o], u);
    u_all[(size_t)cd * 512 + t] = u;
    if (tg == 0) {
        float pk = qs[tid] * kb[tid] + qs[tid + 256] * kb[tid + 256];
        for (int off = 32; off; off >>= 1) pk += __shfl_down(pk, off, 64);
        __shared__ float pr[4];
        if ((tid & 63) == 0) pr[tid >> 6] = pk;
        __syncthreads();
        if (tid == 0) qkbg[cd] = pr[0] + pr[1] + pr[2] + pr[3];
    }
}

// ---------------------------------------------------------------------------
// K7: maxex9[cd][bp][mc] = max over 64-pixel chunk of u.x5[bp,:,m].
// ---------------------------------------------------------------------------
__global__ __launch_bounds__(256)
void refine_max_kernel(const float* __restrict__ x5, const float* __restrict__ u_all,
                       float* __restrict__ maxex9)
{
    int bp = blockIdx.x, cg = blockIdx.y, mc = blockIdx.z;
    int tid = threadIdx.x, mi = tid & 63, cs = tid >> 6;
    int m0 = mc * 64;
    __shared__ float us[16 * 512];   // 32 KB
    __shared__ float red[256];
    for (int e = tid; e < 16 * 512; e += 256) us[e] = u_all[(size_t)cg * 16 * 512 + e];
    __syncthreads();

    float acc[16];
#pragma unroll
    for (int j = 0; j < 16; j++) acc[j] = 0.f;
    const float* xb = x5 + (size_t)bp * CHW + m0 + mi;
    for (int cc = 0; cc < 128; cc++) {
        int c = cs * 128 + cc;
        float x = xb[(size_t)c * HWW];
#pragma unroll
        for (int j = 0; j < 16; j++)
            acc[j] = fmaf(us[j * 512 + c], x, acc[j]);
    }

#pragma unroll
    for (int j = 0; j < 16; j++) {
        red[tid] = acc[j];
        __syncthreads();
        if (tid < 64) {
            float v = red[tid] + red[tid + 64] + red[tid + 128] + red[tid + 192];
            for (int off = 32; off; off >>= 1) v = fmaxf(v, __shfl_xor(v, off, 64));
            if (tid == 0) maxex9[((size_t)(cg * 16 + j) * BB + bp) * 9 + mc] = v;
        }
        __syncthreads();
    }
}

// ---------------------------------------------------------------------------
// K8: exact argmax among candidates -> one-hot mask
// ---------------------------------------------------------------------------
__global__ __launch_bounds__(576)
void mask_kernel(const float* __restrict__ maxex9, const float* __restrict__ qkbg,
                 const int* __restrict__ cand, float* __restrict__ maskout)
{
    int bi = blockIdx.x, m = threadIdx.x;
    __shared__ float ve[4];
    __shared__ int chosen;
    if (m < 4) {
        int cd = bi * 4 + m;
        float sacc = 0.f;
#pragma unroll
        for (int t = 0; t < BB; t++) {
            const float* p = maxex9 + ((size_t)cd * BB + t) * 9;
            float mv = p[0];
#pragma unroll
            for (int z = 1; z < 9; z++) mv = fmaxf(mv, p[z]);
            sacc += mv;
        }
        ve[m] = sacc * (1.f / 16.f) + qkbg[cd];
    }
    __syncthreads();
    if (m == 0) {
        int best = 0; float bv = ve[0];
        for (int j = 1; j < 4; j++) if (ve[j] > bv) { bv = ve[j]; best = j; }
        chosen = cand[bi * 4 + best];
    }
    __syncthreads();
    maskout[bi * HWW + m] = (m == chosen) ? 1.f : 0.f;
}

// ---------------------------------------------------------------------------
// K9..K14: fp32 tail (unchanged)
// ---------------------------------------------------------------------------
__global__ __launch_bounds__(256)
void norm_kernel(const float* __restrict__ X5, float* __restrict__ invb)
{
    int b = blockIdx.y;
    int m0 = blockIdx.x * 64;
    int mi = threadIdx.x & 63, cs = threadIdx.x >> 6;
    float s = 0.f;
    for (int c = cs; c < CC; c += 4) {
        float x = X5[b * CHW + c * HWW + m0 + mi];
        s = fmaf(x, x, s);
    }
    __shared__ float red[4][64];
    red[cs][mi] = s;
    __syncthreads();
    if (cs == 0) {
        float t = red[0][mi] + red[1][mi] + red[2][mi] + red[3][mi];
        invb[b * HWW + m0 + mi] = 1.0f / fmaxf(sqrtf(t), 1e-12f);
    }
}

__global__ __launch_bounds__(256)
void seeds_kernel(const float* __restrict__ X5, const float* __restrict__ invb,
                  const float* __restrict__ maskf, float* __restrict__ seeds)
{
    int s = blockIdx.y;
    int c = blockIdx.x * 4 + (threadIdx.x >> 6);
    int mi = threadIdx.x & 63;
    float acc = 0.f;
    for (int mt = 0; mt < 9; mt++) {
        int m = mt * 64 + mi;
        float w = invb[s * HWW + m] * maskf[s * HWW + m];
        acc = fmaf(X5[s * CHW + c * HWW + m], w, acc);
    }
    for (int off = 32; off > 0; off >>= 1) acc += __shfl_down(acc, off, 64);
    if (mi == 0) seeds[s * CC + c] = acc;
}

__global__ __launch_bounds__(256)
void corr_kernel(const float* __restrict__ X5, const float* __restrict__ invb,
                 const float* __restrict__ seeds, float* __restrict__ corr)
{
    __shared__ float sd[16 * 512];
    __shared__ float xs[64][65];
    __shared__ float red[4][64];
    int b = blockIdx.y;
    int m0 = blockIdx.x * 64;
    int tid = threadIdx.x;
    int mi = tid & 63, sg = tid >> 6;

    for (int e = tid; e < 16 * 512; e += 256) sd[e] = seeds[e];

    float acc[4] = {0.f, 0.f, 0.f, 0.f};
    for (int c0 = 0; c0 < CC; c0 += 64) {
        __syncthreads();
        for (int e = tid; e < 4096; e += 256) {
            int mm = e & 63, kk = e >> 6;
            xs[kk][mm] = X5[b * CHW + (c0 + kk) * HWW + m0 + mm];
        }
        __syncthreads();
#pragma unroll
        for (int kk = 0; kk < 64; kk++) {
            float xv = xs[kk][mi];
#pragma unroll
            for (int t = 0; t < 4; t++)
                acc[t] = fmaf(xv, sd[(sg * 4 + t) * CC + c0 + kk], acc[t]);
        }
    }
    float r = 0.f;
#pragma unroll
    for (int t = 0; t < 4; t++) r += fmaxf(acc[t], 0.f);
    red[sg][mi] = r;
    __syncthreads();
    if (sg == 0) {
        float tot = red[0][mi] + red[1][mi] + red[2][mi] + red[3][mi];
        corr[b * HWW + m0 + mi] = invb[b * HWW + m0 + mi] * tot * (1.0f / 16.0f);
    }
}

__global__ __launch_bounds__(576)
void cormap_kernel(const float* __restrict__ corr, float* __restrict__ cormap)
{
    __shared__ float sv[576];
    __shared__ float smn[64], smx[64];
    __shared__ float s_mn, s_mx;
    int b = blockIdx.x;
    int m = threadIdx.x;
    float v = corr[b * HWW + m];
    sv[m] = v;
    __syncthreads();
    if (m < 64) {
        float mn = sv[m], mx = sv[m];
        for (int j = m + 64; j < 576; j += 64) { mn = fminf(mn, sv[j]); mx = fmaxf(mx, sv[j]); }
        smn[m] = mn; smx[m] = mx;
    }
    __syncthreads();
    if (m == 0) {
        float mn = smn[0], mx = smx[0];
        for (int j = 1; j < 64; j++) { mn = fminf(mn, smn[j]); mx = fmaxf(mx, smx[j]); }
        s_mn = mn; s_mx = mx;
    }
    __syncthreads();
    cormap[b * HWW + m] = (v - s_mn) / (s_mx - s_mn + 1e-12f);
}

__global__ __launch_bounds__(256)
void proto_kernel(const float* __restrict__ X5, const float* __restrict__ cormap,
                  float* __restrict__ proto1)
{
    int c = blockIdx.x;
    int tid = threadIdx.x;
    float acc = 0.f;
    for (int p = tid; p < NN; p += 256) {
        int b = p / HWW, m = p % HWW;
        acc = fmaf(X5[b * CHW + c * HWW + m], cormap[p], acc);
    }
    for (int off = 32; off > 0; off >>= 1) acc += __shfl_down(acc, off, 64);
    __shared__ float red[4];
    if ((tid & 63) == 0) red[tid >> 6] = acc;
    __syncthreads();
    if (tid == 0) proto1[c] = (red[0] + red[1] + red[2] + red[3]) * (1.0f / (float)NN);
}

__global__ __launch_bounds__(256)
void final_kernel(const float* __restrict__ X5, const float* __restrict__ proto1,
                  const float* __restrict__ cormap, float* __restrict__ out3)
{
    int idx = blockIdx.x * 256 + threadIdx.x;
    if (idx >= TOT) return;
    int b = idx / CHW;
    int r = idx % CHW;
    int c = r / HWW;
    int m = r % HWW;
    float x = X5[idx];
    out3[idx] = x * (proto1[c] + cormap[b * HWW + m]);
}

// ---------------------------------------------------------------------------
extern "C" void kernel_launch(void* const* d_in, const int* in_sizes, int n_in,
                              void* d_out, int out_size, void* d_ws, size_t ws_size,
                              hipStream_t stream)
{
    const float* x  = (const float*)d_in[0];
    const float* cw = (const float*)d_in[1];
    const float* cb = (const float*)d_in[2];
    const float* qw = (const float*)d_in[3];
    const float* qb = (const float*)d_in[4];
    const float* kw = (const float*)d_in[5];
    const float* kb = (const float*)d_in[6];

    float* out     = (float*)d_out;
    float* x5o     = out;                        // output 0
    float* proto1  = out + TOT;                  // output 1
    float* out3    = out + TOT + 512;            // output 2
    float* maskout = out + TOT + 512 + TOT;      // output 3

    // out3 region overlays (all consumed before final_kernel writes out3):
    char* o3 = (char*)out3;
    __bf16* xlo    = (__bf16*)o3;
    __bf16* qfrag  = (__bf16*)o3;                // overwrites xlo after conv1
    __bf16* x5frag = (__bf16*)(o3 + FRAGB);

    // ws layout:
    char* ws = (char*)d_ws;
    __bf16* xhi   = (__bf16*)ws;                 // -> later kfrag (same slot)
    __bf16* kfrag = (__bf16*)ws;
    __bf16* cwhi  = (__bf16*)(ws + FRAGB);
    __bf16* cwlo  = (__bf16*)(ws + FRAGB + 524288);
    __bf16* qwf   = (__bf16*)(ws + FRAGB + 2 * 524288);
    __bf16* kwf   = (__bf16*)(ws + FRAGB + 3 * 524288);
    char* p = ws + FRAGB + 4 * 524288;
    float* maxv3  = (float*)p;   p += (size_t)NN * BB * 3 * 4;
    int*   cand   = (int*)p;     p += 256;
    float* q_all  = (float*)p;   p += 64 * 512 * 4;
    float* u_all  = (float*)p;   p += 64 * 512 * 4;
    float* qkbg   = (float*)p;   p += 256;
    float* maxex9 = (float*)p;   p += 64 * BB * 9 * 4;
    float* invb   = (float*)p;   p += NN * 4;
    float* corr   = (float*)p;   p += NN * 4;
    float* cmap   = (float*)p;   p += NN * 4;
    float* seeds  = (float*)p;   p += BB * CC * 4;

    prep_x_kernel<<<NN * 64 / 256, 256, 0, stream>>>(x, xhi, xlo);
    prep_w_kernel<<<dim3(128, 3), 256, 0, stream>>>(cw, qw, kw, cwhi, cwlo, qwf, kwf);

    conv1_mfma_kernel<<<dim3(NN / 128, 4), 256, 0, stream>>>(x, cwhi, cwlo, xhi, xlo, cb, x5o, x5frag);
    convqk_mfma_kernel<<<dim3(NN / 128, 4, 2), 256, 0, stream>>>(qwf, kwf, qb, kb, x5frag, qfrag, kfrag);

    scores_mfma_kernel<<<dim3(NN / 128, BB * 3), 256, 0, stream>>>(qfrag, kfrag, maxv3);

    topk_kernel<<<BB, HWW, 0, stream>>>(maxv3, cand);
    refine_q_kernel<<<dim3(8, 64), 256, 0, stream>>>(x5o, qw, qb, cand, q_all);
    refine_u2_kernel<<<dim3(2, 64), 256, 0, stream>>>(kw, kb, q_all, u_all, qkbg);
    refine_max_kernel<<<dim3(BB, 4, 9), 256, 0, stream>>>(x5o, u_all, maxex9);
    mask_kernel<<<BB, HWW, 0, stream>>>(maxex9, qkbg, cand, maskout);

    norm_kernel<<<dim3(9, BB), 256, 0, stream>>>(x5o, invb);
    seeds_kernel<<<dim3(CC / 4, BB), 256, 0, stream>>>(x5o, invb, maskout, seeds);
    corr_kernel<<<dim3(9, BB), 256, 0, stream>>>(x5o, invb, seeds, corr);
    cormap_kernel<<<BB, HWW, 0, stream>>>(corr, cmap);
    proto_kernel<<<CC, 256, 0, stream>>>(x5o, cmap, proto1);
    final_kernel<<<(TOT + 255) / 256, 256, 0, stream>>>(x5o, proto1, cmap, out3);
}